// Round 1
// baseline (795.856 us; speedup 1.0000x reference)
//
#include <hip/hip_runtime.h>
#include <hip/hip_bf16.h>
#include <math.h>

// Problem constants
#define BB 4
#define SS 128
#define CC 80          // C_MEL
#define HH 256         // D_MODEL
#define KK 9
#define PP 4           // (K-1)/2
#define TT 16          // MAX_DUR
#define NSEG 512       // B*S
#define G3 768         // 3*H
#define EPSV 1e-5f

// ---------------- prep: starts + effective durations ----------------
__global__ __launch_bounds__(512) void k_prep(const int* __restrict__ duration,
                                              const int* __restrict__ srclen,
                                              int* __restrict__ starts,
                                              int* __restrict__ dur) {
  __shared__ int ds[BB][SS];
  int tid = threadIdx.x;               // 0..511
  int b = tid >> 7, s = tid & 127;
  int v = (s < srclen[b]) ? duration[b * SS + s] : 0;
  ds[b][s] = v;
  __syncthreads();
  int run = 0;
  for (int s2 = 0; s2 < s; ++s2) run += ds[b][s2];
  starts[tid] = run;
  dur[tid] = v;
}

// ---------------- conv stack (conv1->BN->relu->mask->conv2->BN->relu->mask) ----
// one block per segment; thread = conv1 output channel dd (256)
__global__ __launch_bounds__(256) void k_conv(
    const float* __restrict__ mel, const int* __restrict__ starts,
    const int* __restrict__ dur, const float* __restrict__ w1,
    const float* __restrict__ g1v, const float* __restrict__ be1v,
    const float* __restrict__ w2, const float* __restrict__ g2v,
    const float* __restrict__ be2v, float* __restrict__ xg, int Mmel) {
  const int seg = blockIdx.x;
  const int b = seg >> 7;
  const int d = dur[seg];
  const int st = starts[seg];
  const int tid = threadIdx.x;

  __shared__ float xs[TT][CC];
  __shared__ float red[4][17];

  for (int idx = tid; idx < TT * CC; idx += 256) {
    int t = idx / CC, c = idx % CC;
    xs[t][c] = (t < d) ? mel[(size_t)(b * Mmel + st + t) * CC + c] : 0.f;
  }

  float w1r[KK], w2r[KK];
#pragma unroll
  for (int k = 0; k < KK; k++) {
    w1r[k] = w1[k * HH + tid];
    w2r[k] = w2[k * HH + tid];
  }
  const float g1 = g1v[tid] * rsqrtf(1.f + EPSV);
  const float be1 = be1v[tid];
  const float g2 = g2v[0] * rsqrtf(1.f + EPSV);
  const float be2 = be2v[0];
  const int lane = tid & 63, wv = tid >> 6;
  __syncthreads();

  for (int c = 0; c < CC; ++c) {
    float xr[TT];
#pragma unroll
    for (int t = 0; t < TT; t++) xr[t] = xs[t][c];

    float y[TT];
#pragma unroll
    for (int t = 0; t < TT; t++) {
      if (t < d) {
        float s = 0.f;
#pragma unroll
        for (int k = 0; k < KK; k++) {
          int u = t + k - PP;
          if (u >= 0 && u < TT) s += w1r[k] * xr[u];
        }
        y[t] = fmaxf(s * g1 + be1, 0.f);
      } else {
        y[t] = 0.f;
      }
    }

#pragma unroll
    for (int t = 0; t < TT; t++) {
      if (t < d) {
        float p = 0.f;
#pragma unroll
        for (int k = 0; k < KK; k++) {
          int u = t + k - PP;
          if (u >= 0 && u < TT) p += w2r[k] * y[u];
        }
#pragma unroll
        for (int off = 32; off > 0; off >>= 1) p += __shfl_xor(p, off, 64);
        if (lane == 0) red[wv][t] = p;
      }
    }
    __syncthreads();
    if (tid < TT) {
      int t = tid;
      float v = 0.f;
      if (t < d) {
        float tot = red[0][t] + red[1][t] + red[2][t] + red[3][t];
        v = fmaxf(tot * g2 + be2, 0.f);
      }
      xg[(size_t)(seg * TT + t) * CC + c] = v;
    }
    __syncthreads();
  }
}

// ---------------- x-gate GEMM: G[8192][1536] = xg[8192][80] @ Wcat^T + b ------
__global__ __launch_bounds__(256) void k_xgate(
    const float* __restrict__ xg, const float* __restrict__ wihf,
    const float* __restrict__ wihb, const float* __restrict__ bihf,
    const float* __restrict__ bihb, float* __restrict__ G) {
  __shared__ float As[CC][68];
  __shared__ float Bs[CC][68];
  const int m0 = blockIdx.x * 64;
  const int n0 = blockIdx.y * 64;
  const int tid = threadIdx.x;
  {
    int row = tid >> 2, kq = tid & 3;
    const float4* src = (const float4*)(xg + (size_t)(m0 + row) * CC);
#pragma unroll
    for (int j = 0; j < 5; j++) {
      float4 v = src[kq * 5 + j];
      int k = (kq * 5 + j) * 4;
      As[k + 0][row] = v.x; As[k + 1][row] = v.y;
      As[k + 2][row] = v.z; As[k + 3][row] = v.w;
    }
    int n = n0 + row;
    const float* bsrc = (n < G3) ? (wihf + (size_t)n * CC)
                                 : (wihb + (size_t)(n - G3) * CC);
    const float4* bs4 = (const float4*)bsrc;
#pragma unroll
    for (int j = 0; j < 5; j++) {
      float4 v = bs4[kq * 5 + j];
      int k = (kq * 5 + j) * 4;
      Bs[k + 0][row] = v.x; Bs[k + 1][row] = v.y;
      Bs[k + 2][row] = v.z; Bs[k + 3][row] = v.w;
    }
  }
  __syncthreads();
  const int tx = tid & 15, ty = tid >> 4;
  float acc[4][4] = {};
#pragma unroll 4
  for (int k = 0; k < CC; k++) {
    float4 a = *(const float4*)&As[k][tx * 4];
    float4 bq = *(const float4*)&Bs[k][ty * 4];
    float av[4] = {a.x, a.y, a.z, a.w};
    float bv[4] = {bq.x, bq.y, bq.z, bq.w};
#pragma unroll
    for (int i = 0; i < 4; i++)
#pragma unroll
      for (int j = 0; j < 4; j++) acc[i][j] += av[i] * bv[j];
  }
  float bb[4];
#pragma unroll
  for (int j = 0; j < 4; j++) {
    int n = n0 + ty * 4 + j;
    bb[j] = (n < G3) ? bihf[n] : bihb[n - G3];
  }
#pragma unroll
  for (int i = 0; i < 4; i++) {
    int m = m0 + tx * 4 + i;
    float4 o;
    o.x = acc[i][0] + bb[0];
    o.y = acc[i][1] + bb[1];
    o.z = acc[i][2] + bb[2];
    o.w = acc[i][3] + bb[3];
    *(float4*)&G[(size_t)m * 1536 + n0 + ty * 4] = o;
  }
}

// ---------------- recurrent step GEMM: HG[1024][768] = h[1024][256] @ whh^T ---
__global__ __launch_bounds__(256) void k_stepgemm(
    const float* __restrict__ hprev, const float* __restrict__ whhf,
    const float* __restrict__ whhb, float* __restrict__ HG, int t) {
  __shared__ float As[32][36];
  __shared__ float Bs[32][36];
  const int m0 = blockIdx.x * 32;  // 0..1023
  const int n0 = blockIdx.y * 32;  // 0..767
  const int tid = threadIdx.x;
  const float* whh = (m0 >= 512) ? whhb : whhf;
  const int tx = tid & 15, ty = tid >> 4;
  float acc[2][2] = {};
  if (t > 0) {
    for (int kk = 0; kk < HH; kk += 32) {
      int row = tid >> 3, kq = tid & 7;
      {
        float4 v = *(const float4*)&hprev[(size_t)(m0 + row) * HH + kk + kq * 4];
        int k = kq * 4;
        As[k][row] = v.x; As[k + 1][row] = v.y;
        As[k + 2][row] = v.z; As[k + 3][row] = v.w;
        float4 w = *(const float4*)&whh[(size_t)(n0 + row) * HH + kk + kq * 4];
        Bs[k][row] = w.x; Bs[k + 1][row] = w.y;
        Bs[k + 2][row] = w.z; Bs[k + 3][row] = w.w;
      }
      __syncthreads();
#pragma unroll
      for (int k = 0; k < 32; k++) {
        float2 a = *(const float2*)&As[k][tx * 2];
        float2 b = *(const float2*)&Bs[k][ty * 2];
        acc[0][0] += a.x * b.x; acc[0][1] += a.x * b.y;
        acc[1][0] += a.y * b.x; acc[1][1] += a.y * b.y;
      }
      __syncthreads();
    }
  }
#pragma unroll
  for (int i = 0; i < 2; i++) {
    int m = m0 + tx * 2 + i;
    float2 o = make_float2(acc[i][0], acc[i][1]);
    *(float2*)&HG[(size_t)m * G3 + n0 + ty * 2] = o;
  }
}

// ---------------- GRU gate update ----------------
__global__ __launch_bounds__(256) void k_update(
    const float* __restrict__ G, const float* __restrict__ HG,
    const float* __restrict__ hprev, float* __restrict__ hout,
    const float* __restrict__ bhhf, const float* __restrict__ bhhb,
    const int* __restrict__ dur, int t) {
  int p = blockIdx.x;    // 0..1023 (dir*512+seg)
  int i = threadIdx.x;   // 0..255
  int dir = p >> 9, seg = p & 511;
  int d = dur[seg];
  float hold = (t == 0) ? 0.f : hprev[(size_t)p * HH + i];
  float hnew = hold;
  if (t < d) {
    int tt = dir ? (d - 1 - t) : t;
    const float* g = G + (size_t)(seg * TT + tt) * 1536 + dir * G3;
    float xr = g[i], xz = g[HH + i], xn = g[2 * HH + i];
    const float* bh = dir ? bhhb : bhhf;
    const float* hg = HG + (size_t)p * G3;
    float hr = hg[i] + bh[i];
    float hz = hg[HH + i] + bh[HH + i];
    float hn = hg[2 * HH + i] + bh[2 * HH + i];
    float r = 1.f / (1.f + expf(-(xr + hr)));
    float z = 1.f / (1.f + expf(-(xz + hz)));
    float n = tanhf(xn + r * hn);
    hnew = (1.f - z) * n + z * hold;
  }
  hout[(size_t)p * HH + i] = hnew;
}

// ---------------- output assembly ----------------
__global__ __launch_bounds__(256) void k_output(const float* __restrict__ hfinal,
                                                const int* __restrict__ srclen,
                                                float* __restrict__ out) {
  int idx = blockIdx.x * 256 + threadIdx.x;  // 0..262143
  int c = idx & 511;
  int seg = idx >> 9;
  int b = seg >> 7, s = seg & 127;
  float v = 0.f;
  if (s < srclen[b]) {
    int dir = c >> 8;
    int i = c & 255;
    v = hfinal[(size_t)(dir * 512 + seg) * HH + i];
  }
  out[idx] = v;
}

extern "C" void kernel_launch(void* const* d_in, const int* in_sizes, int n_in,
                              void* d_out, int out_size, void* d_ws, size_t ws_size,
                              hipStream_t stream) {
  const float* mel = (const float*)d_in[0];
  const int Mmel = in_sizes[0] / (BB * CC);
  const int* duration = (const int*)d_in[2];
  const int* src_len = (const int*)d_in[3];
  const float* conv1_w = (const float*)d_in[5];
  const float* bn1_g = (const float*)d_in[6];
  const float* bn1_b = (const float*)d_in[7];
  const float* conv2_w = (const float*)d_in[8];
  const float* bn2_g = (const float*)d_in[9];
  const float* bn2_b = (const float*)d_in[10];
  const float* w_ih_f = (const float*)d_in[11];
  const float* w_hh_f = (const float*)d_in[12];
  const float* b_ih_f = (const float*)d_in[13];
  const float* b_hh_f = (const float*)d_in[14];
  const float* w_ih_b = (const float*)d_in[15];
  const float* w_hh_b = (const float*)d_in[16];
  const float* b_ih_b = (const float*)d_in[17];
  const float* b_hh_b = (const float*)d_in[18];

  char* w = (char*)d_ws;
  int* starts = (int*)w;            w += 512 * sizeof(int);
  int* dur = (int*)w;               w += 512 * sizeof(int);
  float* xg = (float*)w;            w += (size_t)NSEG * TT * CC * sizeof(float);     // 2.62 MB
  float* G = (float*)w;             w += (size_t)NSEG * TT * 1536 * sizeof(float);   // 50.3 MB
  float* HG = (float*)w;            w += (size_t)1024 * G3 * sizeof(float);          // 3.1 MB
  float* h0 = (float*)w;            w += (size_t)1024 * HH * sizeof(float);
  float* h1 = (float*)w;            w += (size_t)1024 * HH * sizeof(float);
  (void)ws_size; (void)n_in; (void)out_size;

  k_prep<<<1, 512, 0, stream>>>(duration, src_len, starts, dur);
  k_conv<<<NSEG, 256, 0, stream>>>(mel, starts, dur, conv1_w, bn1_g, bn1_b,
                                   conv2_w, bn2_g, bn2_b, xg, Mmel);
  k_xgate<<<dim3(128, 24), 256, 0, stream>>>(xg, w_ih_f, w_ih_b, b_ih_f, b_ih_b, G);

  float* hbuf[2] = {h0, h1};
  for (int t = 0; t < TT; t++) {
    const float* hp = hbuf[(t + 1) & 1];
    float* hn = hbuf[t & 1];
    k_stepgemm<<<dim3(32, 24), 256, 0, stream>>>(hp, w_hh_f, w_hh_b, HG, t);
    k_update<<<1024, 256, 0, stream>>>(G, HG, hp, hn, b_hh_f, b_hh_b, dur, t);
  }
  k_output<<<1024, 256, 0, stream>>>(hbuf[1], src_len, (float*)d_out);
}

// Round 2
// 420.403 us; speedup vs baseline: 1.8931x; 1.8931x over previous
//
#include <hip/hip_runtime.h>
#include <hip/hip_bf16.h>
#include <math.h>

// Problem constants
#define BB 4
#define SS 128
#define CC 80          // C_MEL
#define HH 256         // D_MODEL
#define KK 9
#define PP 4           // (K-1)/2
#define TT 16          // MAX_DUR
#define NSEG 512       // B*S
#define G3 768         // 3*H
#define EPSV 1e-5f

// ---------------- prep: starts + effective durations ----------------
__global__ __launch_bounds__(512) void k_prep(const int* __restrict__ duration,
                                              const int* __restrict__ srclen,
                                              int* __restrict__ starts,
                                              int* __restrict__ dur) {
  __shared__ int ds[BB][SS];
  int tid = threadIdx.x;               // 0..511
  int b = tid >> 7, s = tid & 127;
  int v = (s < srclen[b]) ? duration[b * SS + s] : 0;
  ds[b][s] = v;
  __syncthreads();
  int run = 0;
  for (int s2 = 0; s2 < s; ++s2) run += ds[b][s2];
  starts[tid] = run;
  dur[tid] = v;
}

// ---------------- conv stack: one wave per (seg, c) ----------------
// wave handles all 16 t x 256 h for one (segment, mel-channel) pair.
// lane covers h = lane + 64*i, i=0..3. Butterfly-reduce conv2 over h.
__global__ __launch_bounds__(256) void k_conv(
    const float* __restrict__ mel, const int* __restrict__ starts,
    const int* __restrict__ dur, const float* __restrict__ w1,
    const float* __restrict__ g1v, const float* __restrict__ be1v,
    const float* __restrict__ w2, const float* __restrict__ g2v,
    const float* __restrict__ be2v, float* __restrict__ xg, int Mmel) {
  const int wid = (blockIdx.x * 256 + threadIdx.x) >> 6;  // 0..40959
  const int lane = threadIdx.x & 63;
  const int seg = wid / CC;
  const int c = wid - seg * CC;
  const int b = seg >> 7;
  const int d = dur[seg];
  const int st = starts[seg];

  // load this channel's time series, broadcast to all lanes
  float xv = 0.f;
  if (lane < TT && lane < d)
    xv = mel[(size_t)(b * Mmel + st + lane) * CC + c];
  float xr[TT];
#pragma unroll
  for (int t = 0; t < TT; t++) xr[t] = __shfl(xv, t, 64);

  const float g2 = g2v[0] * rsqrtf(1.f + EPSV);
  const float be2 = be2v[0];

  float q[TT];
#pragma unroll
  for (int t = 0; t < TT; t++) q[t] = 0.f;

#pragma unroll
  for (int i = 0; i < 4; i++) {
    const int h = lane + 64 * i;
    float w1r[KK], w2r[KK];
#pragma unroll
    for (int k = 0; k < KK; k++) {
      w1r[k] = w1[k * HH + h];
      w2r[k] = w2[k * HH + h];
    }
    const float g1 = g1v[h] * rsqrtf(1.f + EPSV);
    const float be1 = be1v[h];

    float y[TT];
#pragma unroll
    for (int t = 0; t < TT; t++) {
      float s = 0.f;
#pragma unroll
      for (int k = 0; k < KK; k++) {
        int u = t + k - PP;
        if (u >= 0 && u < TT) s += w1r[k] * xr[u];
      }
      y[t] = (t < d) ? fmaxf(s * g1 + be1, 0.f) : 0.f;
    }
#pragma unroll
    for (int t = 0; t < TT; t++) {
      float p = q[t];
#pragma unroll
      for (int k = 0; k < KK; k++) {
        int u = t + k - PP;
        if (u >= 0 && u < TT) p += w2r[k] * y[u];
      }
      q[t] = p;
    }
  }

  // butterfly-reduce each q[t] across the 64 lanes
#pragma unroll
  for (int t = 0; t < TT; t++) {
#pragma unroll
    for (int off = 1; off < 64; off <<= 1) q[t] += __shfl_xor(q[t], off, 64);
  }

  if (lane < TT) {
    float qq = 0.f;
#pragma unroll
    for (int t = 0; t < TT; t++)
      if (lane == t) qq = q[t];
    float v = (lane < d) ? fmaxf(qq * g2 + be2, 0.f) : 0.f;
    xg[(size_t)(seg * TT + lane) * CC + c] = v;
  }
}

// ---------------- x-gate GEMM: G[8192][1536] = xg[8192][80] @ Wcat^T + b ------
__global__ __launch_bounds__(256) void k_xgate(
    const float* __restrict__ xg, const float* __restrict__ wihf,
    const float* __restrict__ wihb, const float* __restrict__ bihf,
    const float* __restrict__ bihb, float* __restrict__ G) {
  __shared__ float As[CC][68];
  __shared__ float Bs[CC][68];
  const int m0 = blockIdx.x * 64;
  const int n0 = blockIdx.y * 64;
  const int tid = threadIdx.x;
  {
    int row = tid >> 2, kq = tid & 3;
    const float4* src = (const float4*)(xg + (size_t)(m0 + row) * CC);
#pragma unroll
    for (int j = 0; j < 5; j++) {
      float4 v = src[kq * 5 + j];
      int k = (kq * 5 + j) * 4;
      As[k + 0][row] = v.x; As[k + 1][row] = v.y;
      As[k + 2][row] = v.z; As[k + 3][row] = v.w;
    }
    int n = n0 + row;
    const float* bsrc = (n < G3) ? (wihf + (size_t)n * CC)
                                 : (wihb + (size_t)(n - G3) * CC);
    const float4* bs4 = (const float4*)bsrc;
#pragma unroll
    for (int j = 0; j < 5; j++) {
      float4 v = bs4[kq * 5 + j];
      int k = (kq * 5 + j) * 4;
      Bs[k + 0][row] = v.x; Bs[k + 1][row] = v.y;
      Bs[k + 2][row] = v.z; Bs[k + 3][row] = v.w;
    }
  }
  __syncthreads();
  const int tx = tid & 15, ty = tid >> 4;
  float acc[4][4] = {};
#pragma unroll 4
  for (int k = 0; k < CC; k++) {
    float4 a = *(const float4*)&As[k][tx * 4];
    float4 bq = *(const float4*)&Bs[k][ty * 4];
    float av[4] = {a.x, a.y, a.z, a.w};
    float bv[4] = {bq.x, bq.y, bq.z, bq.w};
#pragma unroll
    for (int i = 0; i < 4; i++)
#pragma unroll
      for (int j = 0; j < 4; j++) acc[i][j] += av[i] * bv[j];
  }
  float bb[4];
#pragma unroll
  for (int j = 0; j < 4; j++) {
    int n = n0 + ty * 4 + j;
    bb[j] = (n < G3) ? bihf[n] : bihb[n - G3];
  }
#pragma unroll
  for (int i = 0; i < 4; i++) {
    int m = m0 + tx * 4 + i;
    float4 o;
    o.x = acc[i][0] + bb[0];
    o.y = acc[i][1] + bb[1];
    o.z = acc[i][2] + bb[2];
    o.w = acc[i][3] + bb[3];
    *(float4*)&G[(size_t)m * 1536 + n0 + ty * 4] = o;
  }
}

// ---------------- recurrent step GEMM: HG[1024][768] = h[1024][256] @ whh^T ---
__global__ __launch_bounds__(256) void k_stepgemm(
    const float* __restrict__ hprev, const float* __restrict__ whhf,
    const float* __restrict__ whhb, float* __restrict__ HG, int t) {
  __shared__ float As[32][36];
  __shared__ float Bs[32][36];
  const int m0 = blockIdx.x * 32;  // 0..1023
  const int n0 = blockIdx.y * 32;  // 0..767
  const int tid = threadIdx.x;
  const float* whh = (m0 >= 512) ? whhb : whhf;
  const int tx = tid & 15, ty = tid >> 4;
  float acc[2][2] = {};
  if (t > 0) {
    for (int kk = 0; kk < HH; kk += 32) {
      int row = tid >> 3, kq = tid & 7;
      {
        float4 v = *(const float4*)&hprev[(size_t)(m0 + row) * HH + kk + kq * 4];
        int k = kq * 4;
        As[k][row] = v.x; As[k + 1][row] = v.y;
        As[k + 2][row] = v.z; As[k + 3][row] = v.w;
        float4 w = *(const float4*)&whh[(size_t)(n0 + row) * HH + kk + kq * 4];
        Bs[k][row] = w.x; Bs[k + 1][row] = w.y;
        Bs[k + 2][row] = w.z; Bs[k + 3][row] = w.w;
      }
      __syncthreads();
#pragma unroll
      for (int k = 0; k < 32; k++) {
        float2 a = *(const float2*)&As[k][tx * 2];
        float2 b = *(const float2*)&Bs[k][ty * 2];
        acc[0][0] += a.x * b.x; acc[0][1] += a.x * b.y;
        acc[1][0] += a.y * b.x; acc[1][1] += a.y * b.y;
      }
      __syncthreads();
    }
  }
#pragma unroll
  for (int i = 0; i < 2; i++) {
    int m = m0 + tx * 2 + i;
    float2 o = make_float2(acc[i][0], acc[i][1]);
    *(float2*)&HG[(size_t)m * G3 + n0 + ty * 2] = o;
  }
}

// ---------------- GRU gate update ----------------
__global__ __launch_bounds__(256) void k_update(
    const float* __restrict__ G, const float* __restrict__ HG,
    const float* __restrict__ hprev, float* __restrict__ hout,
    const float* __restrict__ bhhf, const float* __restrict__ bhhb,
    const int* __restrict__ dur, int t) {
  int p = blockIdx.x;    // 0..1023 (dir*512+seg)
  int i = threadIdx.x;   // 0..255
  int dir = p >> 9, seg = p & 511;
  int d = dur[seg];
  float hold = (t == 0) ? 0.f : hprev[(size_t)p * HH + i];
  float hnew = hold;
  if (t < d) {
    int tt = dir ? (d - 1 - t) : t;
    const float* g = G + (size_t)(seg * TT + tt) * 1536 + dir * G3;
    float xr = g[i], xz = g[HH + i], xn = g[2 * HH + i];
    const float* bh = dir ? bhhb : bhhf;
    const float* hg = HG + (size_t)p * G3;
    float hr = hg[i] + bh[i];
    float hz = hg[HH + i] + bh[HH + i];
    float hn = hg[2 * HH + i] + bh[2 * HH + i];
    float r = 1.f / (1.f + expf(-(xr + hr)));
    float z = 1.f / (1.f + expf(-(xz + hz)));
    float n = tanhf(xn + r * hn);
    hnew = (1.f - z) * n + z * hold;
  }
  hout[(size_t)p * HH + i] = hnew;
}

// ---------------- output assembly ----------------
__global__ __launch_bounds__(256) void k_output(const float* __restrict__ hfinal,
                                                const int* __restrict__ srclen,
                                                float* __restrict__ out) {
  int idx = blockIdx.x * 256 + threadIdx.x;  // 0..262143
  int c = idx & 511;
  int seg = idx >> 9;
  int b = seg >> 7, s = seg & 127;
  float v = 0.f;
  if (s < srclen[b]) {
    int dir = c >> 8;
    int i = c & 255;
    v = hfinal[(size_t)(dir * 512 + seg) * HH + i];
  }
  out[idx] = v;
}

extern "C" void kernel_launch(void* const* d_in, const int* in_sizes, int n_in,
                              void* d_out, int out_size, void* d_ws, size_t ws_size,
                              hipStream_t stream) {
  const float* mel = (const float*)d_in[0];
  const int Mmel = in_sizes[0] / (BB * CC);
  const int* duration = (const int*)d_in[2];
  const int* src_len = (const int*)d_in[3];
  const float* conv1_w = (const float*)d_in[5];
  const float* bn1_g = (const float*)d_in[6];
  const float* bn1_b = (const float*)d_in[7];
  const float* conv2_w = (const float*)d_in[8];
  const float* bn2_g = (const float*)d_in[9];
  const float* bn2_b = (const float*)d_in[10];
  const float* w_ih_f = (const float*)d_in[11];
  const float* w_hh_f = (const float*)d_in[12];
  const float* b_ih_f = (const float*)d_in[13];
  const float* b_hh_f = (const float*)d_in[14];
  const float* w_ih_b = (const float*)d_in[15];
  const float* w_hh_b = (const float*)d_in[16];
  const float* b_ih_b = (const float*)d_in[17];
  const float* b_hh_b = (const float*)d_in[18];

  char* w = (char*)d_ws;
  int* starts = (int*)w;            w += 512 * sizeof(int);
  int* dur = (int*)w;               w += 512 * sizeof(int);
  float* xg = (float*)w;            w += (size_t)NSEG * TT * CC * sizeof(float);     // 2.62 MB
  float* G = (float*)w;             w += (size_t)NSEG * TT * 1536 * sizeof(float);   // 50.3 MB
  float* HG = (float*)w;            w += (size_t)1024 * G3 * sizeof(float);          // 3.1 MB
  float* h0 = (float*)w;            w += (size_t)1024 * HH * sizeof(float);
  float* h1 = (float*)w;            w += (size_t)1024 * HH * sizeof(float);
  (void)ws_size; (void)n_in; (void)out_size;

  k_prep<<<1, 512, 0, stream>>>(duration, src_len, starts, dur);
  // 40960 waves, 4 per block
  k_conv<<<10240, 256, 0, stream>>>(mel, starts, dur, conv1_w, bn1_g, bn1_b,
                                    conv2_w, bn2_g, bn2_b, xg, Mmel);
  k_xgate<<<dim3(128, 24), 256, 0, stream>>>(xg, w_ih_f, w_ih_b, b_ih_f, b_ih_b, G);

  float* hbuf[2] = {h0, h1};
  for (int t = 0; t < TT; t++) {
    const float* hp = hbuf[(t + 1) & 1];
    float* hn = hbuf[t & 1];
    k_stepgemm<<<dim3(32, 24), 256, 0, stream>>>(hp, w_hh_f, w_hh_b, HG, t);
    k_update<<<1024, 256, 0, stream>>>(G, HG, hp, hn, b_hh_f, b_hh_b, dur, t);
  }
  k_output<<<1024, 256, 0, stream>>>(hbuf[1], src_len, (float*)d_out);
}

// Round 3
// 237.495 us; speedup vs baseline: 3.3510x; 1.7702x over previous
//
#include <hip/hip_runtime.h>
#include <hip/hip_bf16.h>
#include <math.h>

// Problem constants
#define BB 4
#define SS 128
#define CC 80          // C_MEL
#define HH 256         // D_MODEL
#define KK 9
#define PP 4           // (K-1)/2
#define TT 16          // MAX_DUR
#define NSEG 512       // B*S
#define G3 768         // 3*H
#define EPSV 1e-5f

typedef short bf16x8 __attribute__((ext_vector_type(8)));
typedef float f32x4 __attribute__((ext_vector_type(4)));

#define HSTR 264       // h_lds stride (bf16 elems)
#define GSTR 770       // hg_lds stride (f32) — 770%8==2 -> conflict-free frag writes

__device__ inline ushort f2bf(float f) {
  unsigned x = __float_as_uint(f);
  unsigned r = (x + 0x7FFF + ((x >> 16) & 1)) >> 16;  // RNE
  return (ushort)r;
}

// ---------------- prep: starts, durations, duration-sorted seg permutation ----
__global__ __launch_bounds__(512) void k_prep(const int* __restrict__ duration,
                                              const int* __restrict__ srclen,
                                              int* __restrict__ starts,
                                              int* __restrict__ dur,
                                              int* __restrict__ perm) {
  __shared__ int ds[512];
  __shared__ int hist[17];
  __shared__ int base[17];
  int tid = threadIdx.x;               // 0..511
  int b = tid >> 7, s = tid & 127;
  int v = (s < srclen[b]) ? duration[b * SS + s] : 0;
  ds[tid] = v;
  if (tid < 17) hist[tid] = 0;
  __syncthreads();
  int run = 0;
  for (int s2 = b * 128; s2 < tid; ++s2) run += ds[s2];
  starts[tid] = run;
  dur[tid] = v;
  atomicAdd(&hist[v], 1);
  __syncthreads();
  if (tid == 0) {
    int acc = 0;
    for (int q = 0; q < 17; q++) { base[q] = acc; acc += hist[q]; }
  }
  __syncthreads();
  int rank = atomicAdd(&base[v], 1);
  perm[rank] = tid;
}

// ---------------- conv stack: one wave per (seg, c) ----------------
__global__ __launch_bounds__(256) void k_conv(
    const float* __restrict__ mel, const int* __restrict__ starts,
    const int* __restrict__ dur, const float* __restrict__ w1,
    const float* __restrict__ g1v, const float* __restrict__ be1v,
    const float* __restrict__ w2, const float* __restrict__ g2v,
    const float* __restrict__ be2v, float* __restrict__ xg, int Mmel) {
  const int wid = (blockIdx.x * 256 + threadIdx.x) >> 6;  // 0..40959
  const int lane = threadIdx.x & 63;
  const int seg = wid / CC;
  const int c = wid - seg * CC;
  const int b = seg >> 7;
  const int d = dur[seg];
  const int st = starts[seg];

  float xv = 0.f;
  if (lane < TT && lane < d)
    xv = mel[(size_t)(b * Mmel + st + lane) * CC + c];
  float xr[TT];
#pragma unroll
  for (int t = 0; t < TT; t++) xr[t] = __shfl(xv, t, 64);

  const float g2 = g2v[0] * rsqrtf(1.f + EPSV);
  const float be2 = be2v[0];

  float q[TT];
#pragma unroll
  for (int t = 0; t < TT; t++) q[t] = 0.f;

#pragma unroll
  for (int i = 0; i < 4; i++) {
    const int h = lane + 64 * i;
    float w1r[KK], w2r[KK];
#pragma unroll
    for (int k = 0; k < KK; k++) {
      w1r[k] = w1[k * HH + h];
      w2r[k] = w2[k * HH + h];
    }
    const float g1 = g1v[h] * rsqrtf(1.f + EPSV);
    const float be1 = be1v[h];

    float y[TT];
#pragma unroll
    for (int t = 0; t < TT; t++) {
      float s = 0.f;
#pragma unroll
      for (int k = 0; k < KK; k++) {
        int u = t + k - PP;
        if (u >= 0 && u < TT) s += w1r[k] * xr[u];
      }
      y[t] = (t < d) ? fmaxf(s * g1 + be1, 0.f) : 0.f;
    }
#pragma unroll
    for (int t = 0; t < TT; t++) {
      float p = q[t];
#pragma unroll
      for (int k = 0; k < KK; k++) {
        int u = t + k - PP;
        if (u >= 0 && u < TT) p += w2r[k] * y[u];
      }
      q[t] = p;
    }
  }

#pragma unroll
  for (int t = 0; t < TT; t++) {
#pragma unroll
    for (int off = 1; off < 64; off <<= 1) q[t] += __shfl_xor(q[t], off, 64);
  }

  if (lane < TT) {
    float qq = 0.f;
#pragma unroll
    for (int t = 0; t < TT; t++)
      if (lane == t) qq = q[t];
    float v = (lane < d) ? fmaxf(qq * g2 + be2, 0.f) : 0.f;
    xg[(size_t)(seg * TT + lane) * CC + c] = v;
  }
}

// ---------------- x-gate GEMM: G[8192][1536] = xg[8192][80] @ Wcat^T + b ------
__global__ __launch_bounds__(256) void k_xgate(
    const float* __restrict__ xg, const float* __restrict__ wihf,
    const float* __restrict__ wihb, const float* __restrict__ bihf,
    const float* __restrict__ bihb, float* __restrict__ G) {
  __shared__ float As[CC][68];
  __shared__ float Bs[CC][68];
  const int m0 = blockIdx.x * 64;
  const int n0 = blockIdx.y * 64;
  const int tid = threadIdx.x;
  {
    int row = tid >> 2, kq = tid & 3;
    const float4* src = (const float4*)(xg + (size_t)(m0 + row) * CC);
#pragma unroll
    for (int j = 0; j < 5; j++) {
      float4 v = src[kq * 5 + j];
      int k = (kq * 5 + j) * 4;
      As[k + 0][row] = v.x; As[k + 1][row] = v.y;
      As[k + 2][row] = v.z; As[k + 3][row] = v.w;
    }
    int n = n0 + row;
    const float* bsrc = (n < G3) ? (wihf + (size_t)n * CC)
                                 : (wihb + (size_t)(n - G3) * CC);
    const float4* bs4 = (const float4*)bsrc;
#pragma unroll
    for (int j = 0; j < 5; j++) {
      float4 v = bs4[kq * 5 + j];
      int k = (kq * 5 + j) * 4;
      Bs[k + 0][row] = v.x; Bs[k + 1][row] = v.y;
      Bs[k + 2][row] = v.z; Bs[k + 3][row] = v.w;
    }
  }
  __syncthreads();
  const int tx = tid & 15, ty = tid >> 4;
  float acc[4][4] = {};
#pragma unroll 4
  for (int k = 0; k < CC; k++) {
    float4 a = *(const float4*)&As[k][tx * 4];
    float4 bq = *(const float4*)&Bs[k][ty * 4];
    float av[4] = {a.x, a.y, a.z, a.w};
    float bv[4] = {bq.x, bq.y, bq.z, bq.w};
#pragma unroll
    for (int i = 0; i < 4; i++)
#pragma unroll
      for (int j = 0; j < 4; j++) acc[i][j] += av[i] * bv[j];
  }
  float bb[4];
#pragma unroll
  for (int j = 0; j < 4; j++) {
    int n = n0 + ty * 4 + j;
    bb[j] = (n < G3) ? bihf[n] : bihb[n - G3];
  }
#pragma unroll
  for (int i = 0; i < 4; i++) {
    int m = m0 + tx * 4 + i;
    float4 o;
    o.x = acc[i][0] + bb[0];
    o.y = acc[i][1] + bb[1];
    o.z = acc[i][2] + bb[2];
    o.w = acc[i][3] + bb[3];
    *(float4*)&G[(size_t)m * 1536 + n0 + ty * 4] = o;
  }
}

// ---------------- pack whh (both dirs) into bf16 MFMA-fragment order ----------
// idx = (((dir*8 + w)*6 + nt)*8 + ks)*512 + lane*8 + j
// value = whh_dir[n][k], n = w*96 + nt*16 + (lane&15), k = ks*32 + (lane>>4)*8 + j
__global__ __launch_bounds__(256) void k_wpack(const float* __restrict__ whhf,
                                               const float* __restrict__ whhb,
                                               ushort* __restrict__ wp) {
  int tid = blockIdx.x * 256 + threadIdx.x;   // 0..393215
  int r = tid;
  int j = r & 7; r >>= 3;
  int lane = r & 63; r >>= 6;
  int ks = r & 7; r >>= 3;
  int nt = r % 6; r /= 6;
  int w = r & 7; r >>= 3;
  int dir = r;
  int n = w * 96 + nt * 16 + (lane & 15);
  int k = ks * 32 + (lane >> 4) * 8 + j;
  float v = (dir ? whhb : whhf)[(size_t)n * HH + k];
  wp[tid] = f2bf(v);
}

// ---------------- fused bidirectional GRU: one launch, block-local recurrence --
// 64 blocks x 512 threads; block bi: dir = bi>>5, 16 segs = perm[(bi&31)*16 ..]
__global__ __launch_bounds__(512) void k_gru(
    const float* __restrict__ G, const ushort* __restrict__ wp,
    const float* __restrict__ bhhf, const float* __restrict__ bhhb,
    const int* __restrict__ dur, const int* __restrict__ perm,
    float* __restrict__ out) {
  __shared__ short h_lds[16 * HSTR];    // bf16 h, padded stride
  __shared__ float hg[16 * GSTR];       // gate pre-activations
  __shared__ int seg_s[16], d_s[16];

  const int tid = threadIdx.x;
  const int bi = blockIdx.x;           // 0..63
  const int dir = bi >> 5;
  const int grp = bi & 31;

  if (tid < 16) {
    int seg = perm[grp * 16 + tid];
    seg_s[tid] = seg;
    d_s[tid] = dur[seg];
  }
  for (int idx = tid; idx < 16 * HSTR; idx += 512) h_lds[idx] = 0;
  __syncthreads();

  // update-phase mapping: pair p = tid>>5, strided channels i = ib + 32*j
  const int p = tid >> 5;
  const int ib = tid & 31;
  const int d_p = d_s[p];
  const int seg_p = seg_s[p];
  const float* bh = dir ? bhhb : bhhf;
  float brv[8], bzv[8], bnv[8];
#pragma unroll
  for (int j = 0; j < 8; j++) {
    int i = ib + 32 * j;
    brv[j] = bh[i]; bzv[j] = bh[256 + i]; bnv[j] = bh[512 + i];
  }
  float h[8];
#pragma unroll
  for (int j = 0; j < 8; j++) h[j] = 0.f;

  // MFMA-phase mapping
  const int wv = tid >> 6;             // wave 0..7 -> n-slice [96w, 96w+96)
  const int lane = tid & 63;
  const int lrow = lane & 15;
  const int lgrp = lane >> 4;
  const ushort* wbase = wp + (size_t)(dir * 8 + wv) * 24576 + lane * 8;
  const int n0 = wv * 96;

  int dmax = 0;
#pragma unroll
  for (int q = 0; q < 16; q++) dmax = max(dmax, d_s[q]);

  for (int t = 0; t < dmax; t++) {
    // ---- MFMA phase: hg = h @ whh^T (bf16 in, fp32 acc) ----
    bf16x8 a[8];
#pragma unroll
    for (int ks = 0; ks < 8; ks++)
      a[ks] = *(const bf16x8*)&h_lds[lrow * HSTR + ks * 32 + lgrp * 8];
    f32x4 acc[6];
#pragma unroll
    for (int nt = 0; nt < 6; nt++) {
      f32x4 c = {0.f, 0.f, 0.f, 0.f};
#pragma unroll
      for (int ks = 0; ks < 8; ks++) {
        bf16x8 wf = *(const bf16x8*)&wbase[(nt * 8 + ks) * 512];
        c = __builtin_amdgcn_mfma_f32_16x16x32_bf16(a[ks], wf, c, 0, 0, 0);
      }
      acc[nt] = c;
    }
#pragma unroll
    for (int nt = 0; nt < 6; nt++) {
      int n = n0 + nt * 16 + lrow;
#pragma unroll
      for (int r = 0; r < 4; r++)
        hg[(lgrp * 4 + r) * GSTR + n] = acc[nt][r];
    }
    __syncthreads();
    // ---- update phase: pointwise gates ----
    if (t < d_p) {
      int tt = dir ? (d_p - 1 - t) : t;
      const float* g = G + (size_t)(seg_p * TT + tt) * 1536 + dir * G3;
#pragma unroll
      for (int j = 0; j < 8; j++) {
        int i = ib + 32 * j;
        float xr = g[i], xz = g[256 + i], xn = g[512 + i];
        float hr = hg[p * GSTR + i] + brv[j];
        float hz = hg[p * GSTR + 256 + i] + bzv[j];
        float hn = hg[p * GSTR + 512 + i] + bnv[j];
        float rr = 1.f / (1.f + expf(-(xr + hr)));
        float zz = 1.f / (1.f + expf(-(xz + hz)));
        float nn = tanhf(xn + rr * hn);
        h[j] = (1.f - zz) * nn + zz * h[j];
        h_lds[p * HSTR + i] = (short)f2bf(h[j]);
      }
    }
    __syncthreads();
  }

#pragma unroll
  for (int j = 0; j < 8; j++) {
    int i = ib + 32 * j;
    out[(size_t)seg_p * 512 + dir * 256 + i] = h[j];
  }
}

extern "C" void kernel_launch(void* const* d_in, const int* in_sizes, int n_in,
                              void* d_out, int out_size, void* d_ws, size_t ws_size,
                              hipStream_t stream) {
  const float* mel = (const float*)d_in[0];
  const int Mmel = in_sizes[0] / (BB * CC);
  const int* duration = (const int*)d_in[2];
  const int* src_len = (const int*)d_in[3];
  const float* conv1_w = (const float*)d_in[5];
  const float* bn1_g = (const float*)d_in[6];
  const float* bn1_b = (const float*)d_in[7];
  const float* conv2_w = (const float*)d_in[8];
  const float* bn2_g = (const float*)d_in[9];
  const float* bn2_b = (const float*)d_in[10];
  const float* w_ih_f = (const float*)d_in[11];
  const float* w_hh_f = (const float*)d_in[12];
  const float* b_ih_f = (const float*)d_in[13];
  const float* b_hh_f = (const float*)d_in[14];
  const float* w_ih_b = (const float*)d_in[15];
  const float* w_hh_b = (const float*)d_in[16];
  const float* b_ih_b = (const float*)d_in[17];
  const float* b_hh_b = (const float*)d_in[18];

  char* w = (char*)d_ws;
  int* starts = (int*)w;            w += 512 * sizeof(int);
  int* dur = (int*)w;               w += 512 * sizeof(int);
  int* perm = (int*)w;              w += 512 * sizeof(int);
  w += 512 * sizeof(int);           // pad to 16B multiple
  float* xg = (float*)w;            w += (size_t)NSEG * TT * CC * sizeof(float);     // 2.62 MB
  float* G = (float*)w;             w += (size_t)NSEG * TT * 1536 * sizeof(float);   // 50.3 MB
  ushort* wp = (ushort*)w;          w += (size_t)2 * 8 * 6 * 8 * 512 * sizeof(ushort); // 786 KB
  (void)ws_size; (void)n_in; (void)out_size;

  k_prep<<<1, 512, 0, stream>>>(duration, src_len, starts, dur, perm);
  k_wpack<<<1536, 256, 0, stream>>>(w_hh_f, w_hh_b, wp);
  k_conv<<<10240, 256, 0, stream>>>(mel, starts, dur, conv1_w, bn1_g, bn1_b,
                                    conv2_w, bn2_g, bn2_b, xg, Mmel);
  k_xgate<<<dim3(128, 24), 256, 0, stream>>>(xg, w_ih_f, w_ih_b, b_ih_f, b_ih_b, G);
  k_gru<<<64, 512, 0, stream>>>(G, wp, b_hh_f, b_hh_b, dur, perm, (float*)d_out);
}

// Round 4
// 158.681 us; speedup vs baseline: 5.0154x; 1.4967x over previous
//
#include <hip/hip_runtime.h>
#include <hip/hip_bf16.h>
#include <math.h>

// Problem constants
#define BB 4
#define SS 128
#define CC 80          // C_MEL
#define HH 256         // D_MODEL
#define KK 9
#define PP 4           // (K-1)/2
#define TT 16          // MAX_DUR
#define NSEG 512       // B*S
#define G3 768         // 3*H
#define EPSV 1e-5f

typedef short bf16x8 __attribute__((ext_vector_type(8)));
typedef float f32x4 __attribute__((ext_vector_type(4)));

#define HSTR 264       // h_lds row stride in bf16 elems (256 + 8 pad)

__device__ inline ushort f2bf(float f) {
  unsigned x = __float_as_uint(f);
  unsigned r = (x + 0x7FFF + ((x >> 16) & 1)) >> 16;  // RNE
  return (ushort)r;
}
__device__ inline float fsig(float x) { return 1.f / (1.f + __expf(-x)); }
__device__ inline float ftanh(float x) {
  float e = __expf(2.f * x);
  return 1.f - 2.f / (e + 1.f);
}

// ---------------- prep: starts, durations, duration-sorted seg permutation ----
__global__ __launch_bounds__(512) void k_prep(const int* __restrict__ duration,
                                              const int* __restrict__ srclen,
                                              int* __restrict__ starts,
                                              int* __restrict__ dur,
                                              int* __restrict__ perm) {
  __shared__ int ds[512];
  __shared__ int hist[17];
  __shared__ int base[17];
  int tid = threadIdx.x;               // 0..511
  int b = tid >> 7, s = tid & 127;
  int v = (s < srclen[b]) ? duration[b * SS + s] : 0;
  ds[tid] = v;
  if (tid < 17) hist[tid] = 0;
  __syncthreads();
  int run = 0;
  for (int s2 = b * 128; s2 < tid; ++s2) run += ds[s2];
  starts[tid] = run;
  dur[tid] = v;
  atomicAdd(&hist[v], 1);
  __syncthreads();
  if (tid == 0) {
    int acc = 0;
    for (int q = 0; q < 17; q++) { base[q] = acc; acc += hist[q]; }
  }
  __syncthreads();
  int rank = atomicAdd(&base[v], 1);
  perm[rank] = tid;
}

// ---------------- conv stack: one wave per (seg, c) ----------------
__global__ __launch_bounds__(256) void k_conv(
    const float* __restrict__ mel, const int* __restrict__ starts,
    const int* __restrict__ dur, const float* __restrict__ w1,
    const float* __restrict__ g1v, const float* __restrict__ be1v,
    const float* __restrict__ w2, const float* __restrict__ g2v,
    const float* __restrict__ be2v, float* __restrict__ xg, int Mmel) {
  const int wid = (blockIdx.x * 256 + threadIdx.x) >> 6;  // 0..40959
  const int lane = threadIdx.x & 63;
  const int seg = wid / CC;
  const int c = wid - seg * CC;
  const int b = seg >> 7;
  const int d = dur[seg];
  const int st = starts[seg];

  float xv = 0.f;
  if (lane < TT && lane < d)
    xv = mel[(size_t)(b * Mmel + st + lane) * CC + c];
  float xr[TT];
#pragma unroll
  for (int t = 0; t < TT; t++) xr[t] = __shfl(xv, t, 64);

  const float g2 = g2v[0] * rsqrtf(1.f + EPSV);
  const float be2 = be2v[0];

  float q[TT];
#pragma unroll
  for (int t = 0; t < TT; t++) q[t] = 0.f;

#pragma unroll
  for (int i = 0; i < 4; i++) {
    const int h = lane + 64 * i;
    float w1r[KK], w2r[KK];
#pragma unroll
    for (int k = 0; k < KK; k++) {
      w1r[k] = w1[k * HH + h];
      w2r[k] = w2[k * HH + h];
    }
    const float g1 = g1v[h] * rsqrtf(1.f + EPSV);
    const float be1 = be1v[h];

    float y[TT];
#pragma unroll
    for (int t = 0; t < TT; t++) {
      float s = 0.f;
#pragma unroll
      for (int k = 0; k < KK; k++) {
        int u = t + k - PP;
        if (u >= 0 && u < TT) s += w1r[k] * xr[u];
      }
      y[t] = (t < d) ? fmaxf(s * g1 + be1, 0.f) : 0.f;
    }
#pragma unroll
    for (int t = 0; t < TT; t++) {
      float p = q[t];
#pragma unroll
      for (int k = 0; k < KK; k++) {
        int u = t + k - PP;
        if (u >= 0 && u < TT) p += w2r[k] * y[u];
      }
      q[t] = p;
    }
  }

#pragma unroll
  for (int t = 0; t < TT; t++) {
#pragma unroll
    for (int off = 1; off < 64; off <<= 1) q[t] += __shfl_xor(q[t], off, 64);
  }

  if (lane < TT) {
    float qq = 0.f;
#pragma unroll
    for (int t = 0; t < TT; t++)
      if (lane == t) qq = q[t];
    float v = (lane < d) ? fmaxf(qq * g2 + be2, 0.f) : 0.f;
    xg[(size_t)(seg * TT + lane) * CC + c] = v;
  }
}

// ---------------- x-gate GEMM: G[8192][1536] = xg[8192][80] @ Wcat^T + b ------
__global__ __launch_bounds__(256) void k_xgate(
    const float* __restrict__ xg, const float* __restrict__ wihf,
    const float* __restrict__ wihb, const float* __restrict__ bihf,
    const float* __restrict__ bihb, float* __restrict__ G) {
  __shared__ float As[CC][68];
  __shared__ float Bs[CC][68];
  const int m0 = blockIdx.x * 64;
  const int n0 = blockIdx.y * 64;
  const int tid = threadIdx.x;
  {
    int row = tid >> 2, kq = tid & 3;
    const float4* src = (const float4*)(xg + (size_t)(m0 + row) * CC);
#pragma unroll
    for (int j = 0; j < 5; j++) {
      float4 v = src[kq * 5 + j];
      int k = (kq * 5 + j) * 4;
      As[k + 0][row] = v.x; As[k + 1][row] = v.y;
      As[k + 2][row] = v.z; As[k + 3][row] = v.w;
    }
    int n = n0 + row;
    const float* bsrc = (n < G3) ? (wihf + (size_t)n * CC)
                                 : (wihb + (size_t)(n - G3) * CC);
    const float4* bs4 = (const float4*)bsrc;
#pragma unroll
    for (int j = 0; j < 5; j++) {
      float4 v = bs4[kq * 5 + j];
      int k = (kq * 5 + j) * 4;
      Bs[k + 0][row] = v.x; Bs[k + 1][row] = v.y;
      Bs[k + 2][row] = v.z; Bs[k + 3][row] = v.w;
    }
  }
  __syncthreads();
  const int tx = tid & 15, ty = tid >> 4;
  float acc[4][4] = {};
#pragma unroll 4
  for (int k = 0; k < CC; k++) {
    float4 a = *(const float4*)&As[k][tx * 4];
    float4 bq = *(const float4*)&Bs[k][ty * 4];
    float av[4] = {a.x, a.y, a.z, a.w};
    float bv[4] = {bq.x, bq.y, bq.z, bq.w};
#pragma unroll
    for (int i = 0; i < 4; i++)
#pragma unroll
      for (int j = 0; j < 4; j++) acc[i][j] += av[i] * bv[j];
  }
  float bb[4];
#pragma unroll
  for (int j = 0; j < 4; j++) {
    int n = n0 + ty * 4 + j;
    bb[j] = (n < G3) ? bihf[n] : bihb[n - G3];
  }
#pragma unroll
  for (int i = 0; i < 4; i++) {
    int m = m0 + tx * 4 + i;
    float4 o;
    o.x = acc[i][0] + bb[0];
    o.y = acc[i][1] + bb[1];
    o.z = acc[i][2] + bb[2];
    o.w = acc[i][3] + bb[3];
    *(float4*)&G[(size_t)m * 1536 + n0 + ty * 4] = o;
  }
}

// ---------------- pack whh (both dirs) into bf16 MFMA-fragment order ----------
// frag (dir, wv, tau, ks): tau = gate*2 + a
//   n = gate*256 + wv*32 + a*16 + (lane&15)
//   k = ks*32 + (lane>>4)*8 + j
__global__ __launch_bounds__(256) void k_wpack(const float* __restrict__ whhf,
                                               const float* __restrict__ whhb,
                                               ushort* __restrict__ wp) {
  int tid = blockIdx.x * 256 + threadIdx.x;   // 0..393215
  int r = tid;
  int j = r & 7; r >>= 3;
  int lane = r & 63; r >>= 6;
  int ks = r & 7; r >>= 3;
  int tau = r % 6; r /= 6;
  int wv = r & 7; r >>= 3;
  int dir = r;
  int gate = tau >> 1, a = tau & 1;
  int n = gate * 256 + wv * 32 + a * 16 + (lane & 15);
  int k = ks * 32 + (lane >> 4) * 8 + j;
  float v = (dir ? whhb : whhf)[(size_t)n * HH + k];
  wp[tid] = f2bf(v);
}

// ---------------- fused bidirectional GRU: weights register/LDS-resident ------
// 64 blocks x 512 threads; block bi: dir = bi>>5, 16 segs = perm[(bi&31)*16..]
// wave wv owns channels i = wv*32 + a*16 + lrow (a=0,1) of all 3 gates; the
// r/z/n triplet for a channel lives in this lane's acc regs -> no hg exchange.
__global__ __launch_bounds__(512, 2) void k_gru(
    const float* __restrict__ G, const ushort* __restrict__ wp,
    const float* __restrict__ bhhf, const float* __restrict__ bhhb,
    const int* __restrict__ dur, const int* __restrict__ perm,
    float* __restrict__ out) {
  __shared__ short h_lds[2][16 * HSTR];     // 16896 B, double-buffered bf16 h
  __shared__ ushort wlds[8 * 2 * 8 * 512];  // 131072 B: tau=4,5 frags per wave
  __shared__ int seg_s[16], d_s[16];

  const int tid = threadIdx.x;
  const int bi = blockIdx.x;           // 0..63
  const int dir = bi >> 5;
  const int grp = bi & 31;
  const int wv = tid >> 6;
  const int lane = tid & 63;
  const int lrow = lane & 15;
  const int lgrp = lane >> 4;

  if (tid < 16) {
    int seg = perm[grp * 16 + tid];
    seg_s[tid] = seg;
    d_s[tid] = dur[seg];
  }
  for (int idx = tid; idx < 2 * 16 * HSTR; idx += 512)
    ((short*)h_lds)[idx] = 0;

  // weights: tau 0..3 -> registers (128 VGPR), tau 4..5 -> LDS
  const ushort* wb = wp + (size_t)(dir * 8 + wv) * 6 * 8 * 512 + lane * 8;
  bf16x8 wreg[4][8];
#pragma unroll
  for (int tau = 0; tau < 4; tau++)
#pragma unroll
    for (int ks = 0; ks < 8; ks++)
      wreg[tau][ks] = *(const bf16x8*)&wb[(tau * 8 + ks) * 512];
#pragma unroll
  for (int tt2 = 0; tt2 < 2; tt2++)
#pragma unroll
    for (int ks = 0; ks < 8; ks++) {
      bf16x8 v = *(const bf16x8*)&wb[((4 + tt2) * 8 + ks) * 512];
      *(bf16x8*)&wlds[((wv * 2 + tt2) * 8 + ks) * 512 + lane * 8] = v;
    }
  __syncthreads();

  int d4[4], seg4[4];
#pragma unroll
  for (int r = 0; r < 4; r++) {
    d4[r] = d_s[lgrp * 4 + r];
    seg4[r] = seg_s[lgrp * 4 + r];
  }
  int dmax = 0;
#pragma unroll
  for (int q = 0; q < 16; q++) dmax = max(dmax, d_s[q]);

  const int i0 = wv * 32 + lrow;       // channel for a=0 (a=1: +16)
  const float* bh = dir ? bhhb : bhhf;
  float bias[3][2];
#pragma unroll
  for (int g = 0; g < 3; g++)
#pragma unroll
    for (int a = 0; a < 2; a++) bias[g][a] = bh[g * 256 + i0 + 16 * a];

  float h[4][2] = {};

  for (int t = 0; t < dmax; t++) {
    const int cur = t & 1;
    // prefetch this step's x-gate values (consumed after MFMA phase)
    float gx[4][3][2];
#pragma unroll
    for (int r = 0; r < 4; r++) {
      if (t < d4[r]) {
        int ts = dir ? (d4[r] - 1 - t) : t;
        const float* grow = G + (size_t)(seg4[r] * TT + ts) * 1536 + dir * G3;
#pragma unroll
        for (int g = 0; g < 3; g++)
#pragma unroll
          for (int a = 0; a < 2; a++) gx[r][g][a] = grow[g * 256 + i0 + 16 * a];
      }
    }
    // MFMA phase: acc[tau] = h @ whh_slice^T
    f32x4 acc[6];
#pragma unroll
    for (int tau = 0; tau < 6; tau++) acc[tau] = (f32x4){0.f, 0.f, 0.f, 0.f};
#pragma unroll
    for (int ks = 0; ks < 8; ks++) {
      bf16x8 av = *(const bf16x8*)&h_lds[cur][lrow * HSTR + ks * 32 + lgrp * 8];
#pragma unroll
      for (int tau = 0; tau < 4; tau++)
        acc[tau] = __builtin_amdgcn_mfma_f32_16x16x32_bf16(av, wreg[tau][ks],
                                                           acc[tau], 0, 0, 0);
#pragma unroll
      for (int tt2 = 0; tt2 < 2; tt2++) {
        bf16x8 wf = *(const bf16x8*)&wlds[((wv * 2 + tt2) * 8 + ks) * 512 + lane * 8];
        acc[4 + tt2] = __builtin_amdgcn_mfma_f32_16x16x32_bf16(av, wf,
                                                               acc[4 + tt2], 0, 0, 0);
      }
    }
    // gate phase: all in registers; write h (bf16) to the other buffer
#pragma unroll
    for (int r = 0; r < 4; r++) {
      if (t < d4[r]) {
#pragma unroll
        for (int a = 0; a < 2; a++) {
          float rr = fsig(gx[r][0][a] + acc[a][r] + bias[0][a]);
          float zz = fsig(gx[r][1][a] + acc[2 + a][r] + bias[1][a]);
          float nn = ftanh(gx[r][2][a] + rr * (acc[4 + a][r] + bias[2][a]));
          h[r][a] = (1.f - zz) * nn + zz * h[r][a];
          h_lds[cur ^ 1][(lgrp * 4 + r) * HSTR + i0 + 16 * a] = (short)f2bf(h[r][a]);
        }
      }
    }
    __syncthreads();
  }

#pragma unroll
  for (int r = 0; r < 4; r++)
#pragma unroll
    for (int a = 0; a < 2; a++)
      out[(size_t)seg4[r] * 512 + dir * 256 + i0 + 16 * a] = h[r][a];
}

extern "C" void kernel_launch(void* const* d_in, const int* in_sizes, int n_in,
                              void* d_out, int out_size, void* d_ws, size_t ws_size,
                              hipStream_t stream) {
  const float* mel = (const float*)d_in[0];
  const int Mmel = in_sizes[0] / (BB * CC);
  const int* duration = (const int*)d_in[2];
  const int* src_len = (const int*)d_in[3];
  const float* conv1_w = (const float*)d_in[5];
  const float* bn1_g = (const float*)d_in[6];
  const float* bn1_b = (const float*)d_in[7];
  const float* conv2_w = (const float*)d_in[8];
  const float* bn2_g = (const float*)d_in[9];
  const float* bn2_b = (const float*)d_in[10];
  const float* w_ih_f = (const float*)d_in[11];
  const float* w_hh_f = (const float*)d_in[12];
  const float* b_ih_f = (const float*)d_in[13];
  const float* b_hh_f = (const float*)d_in[14];
  const float* w_ih_b = (const float*)d_in[15];
  const float* w_hh_b = (const float*)d_in[16];
  const float* b_ih_b = (const float*)d_in[17];
  const float* b_hh_b = (const float*)d_in[18];

  char* w = (char*)d_ws;
  int* starts = (int*)w;            w += 512 * sizeof(int);
  int* dur = (int*)w;               w += 512 * sizeof(int);
  int* perm = (int*)w;              w += 512 * sizeof(int);
  w += 512 * sizeof(int);           // pad
  float* xg = (float*)w;            w += (size_t)NSEG * TT * CC * sizeof(float);     // 2.62 MB
  float* G = (float*)w;             w += (size_t)NSEG * TT * 1536 * sizeof(float);   // 50.3 MB
  ushort* wp = (ushort*)w;          w += (size_t)2 * 8 * 6 * 8 * 512 * sizeof(ushort); // 786 KB
  (void)ws_size; (void)n_in; (void)out_size;

  k_prep<<<1, 512, 0, stream>>>(duration, src_len, starts, dur, perm);
  k_wpack<<<1536, 256, 0, stream>>>(w_hh_f, w_hh_b, wp);
  k_conv<<<10240, 256, 0, stream>>>(mel, starts, dur, conv1_w, bn1_g, bn1_b,
                                    conv2_w, bn2_g, bn2_b, xg, Mmel);
  k_xgate<<<dim3(128, 24), 256, 0, stream>>>(xg, w_ih_f, w_ih_b, b_ih_f, b_ih_b, G);
  k_gru<<<64, 512, 0, stream>>>(G, wp, b_hh_f, b_hh_b, dur, perm, (float*)d_out);
}

// Round 5
// 142.452 us; speedup vs baseline: 5.5868x; 1.1139x over previous
//
#include <hip/hip_runtime.h>
#include <hip/hip_bf16.h>
#include <math.h>

// Problem constants
#define BB 4
#define SS 128
#define CC 80          // C_MEL
#define HH 256         // D_MODEL
#define KK 9
#define PP 4           // (K-1)/2
#define TT 16          // MAX_DUR
#define NSEG 512       // B*S
#define G3 768         // 3*H
#define EPSV 1e-5f

typedef short bf16x8 __attribute__((ext_vector_type(8)));
typedef float f32x4 __attribute__((ext_vector_type(4)));

#define HSTR 264       // h_lds row stride in bf16 elems (256 + 8 pad)

__device__ inline ushort f2bf(float f) {
  unsigned x = __float_as_uint(f);
  unsigned r = (x + 0x7FFF + ((x >> 16) & 1)) >> 16;  // RNE
  return (ushort)r;
}
__device__ inline float fsig(float x) { return 1.f / (1.f + __expf(-x)); }
__device__ inline float ftanh(float x) {
  float e = __expf(2.f * x);
  return 1.f - 2.f / (e + 1.f);
}

// ---------------- prep: starts, durations, duration-sorted seg permutation ----
__global__ __launch_bounds__(512) void k_prep(const int* __restrict__ duration,
                                              const int* __restrict__ srclen,
                                              int* __restrict__ starts,
                                              int* __restrict__ dur,
                                              int* __restrict__ perm) {
  __shared__ int ds[512];
  __shared__ int hist[17];
  __shared__ int base[17];
  int tid = threadIdx.x;               // 0..511
  int b = tid >> 7, s = tid & 127;
  int v = (s < srclen[b]) ? duration[b * SS + s] : 0;
  ds[tid] = v;
  if (tid < 17) hist[tid] = 0;
  __syncthreads();
  int run = 0;
  for (int s2 = b * 128; s2 < tid; ++s2) run += ds[s2];
  starts[tid] = run;
  dur[tid] = v;
  atomicAdd(&hist[v], 1);
  __syncthreads();
  if (tid == 0) {
    int acc = 0;
    for (int q = 0; q < 17; q++) { base[q] = acc; acc += hist[q]; }
  }
  __syncthreads();
  int rank = atomicAdd(&base[v], 1);
  perm[rank] = tid;
}

// ---------------- pack conv weights into MFMA fragment order (bf16) ----------
// A1 frags (conv1, M=h): wpc[nt*512 + lane*8 + j]:
//   h = nt*16 + (lane&15), k = (lane>>4)*8 + j
//   val = k<9 ? w1[k][h]*g1'[h] : (k==9 ? be1[h] : 0)
// A2 frags (conv2, M=k): wpc[8192 + ks*512 + lane*8 + j]:
//   k = lane&15, h = ks*32 + (lane>>4)*8 + j; val = k<9 ? w2[k][h] : 0
__global__ __launch_bounds__(256) void k_wpackc(const float* __restrict__ w1,
                                                const float* __restrict__ g1v,
                                                const float* __restrict__ be1v,
                                                const float* __restrict__ w2,
                                                ushort* __restrict__ wpc) {
  int tid = blockIdx.x * 256 + threadIdx.x;   // 0..12287
  if (tid < 8192) {
    int nt = tid >> 9;
    int lane = (tid >> 3) & 63;
    int j = tid & 7;
    int h = nt * 16 + (lane & 15);
    int k = (lane >> 4) * 8 + j;
    float val = 0.f;
    if (k < KK) val = w1[k * HH + h] * (g1v[h] * rsqrtf(1.f + EPSV));
    else if (k == KK) val = be1v[h];
    wpc[tid] = f2bf(val);
  } else if (tid < 12288) {
    int q = tid - 8192;
    int ks = q >> 9;
    int lane = (q >> 3) & 63;
    int j = q & 7;
    int k = lane & 15;
    int h = ks * 32 + (lane >> 4) * 8 + j;
    float val = (k < KK) ? w2[k * HH + h] : 0.f;
    wpc[tid] = f2bf(val);
  }
}

// ---------------- conv stack via chained MFMA: 1 block per segment ------------
// conv1: D1[h][u] = sum_k A1[h][k] B1[k][u]; A1 = w1*g1 (+be1 at k=9),
//        B1[k][u] = x[c][u+k-4] (k<9), B1[9][u] = 1.
// relu+mask -> bf16 -> shuffle-transpose -> conv2 B-frags.
// conv2: Z[k][u] = sum_h w2[k][h] Y[h][u]; Q[u] = sum_k Z[k][u+k-4].
__global__ __launch_bounds__(512, 2) void k_conv(
    const float* __restrict__ mel, const int* __restrict__ starts,
    const int* __restrict__ dur, const ushort* __restrict__ wpc,
    const float* __restrict__ g2v, const float* __restrict__ be2v,
    float* __restrict__ xg, int Mmel) {
  __shared__ ushort xs[CC][16];      // bf16 x, zero-padded t>=d
  __shared__ float xgs[16][81];      // staged output (pad 81 -> no conflicts)

  const int seg = blockIdx.x;
  const int b = seg >> 7;
  const int d = dur[seg];
  const int st = starts[seg];
  const int tid = threadIdx.x;
  const int wv = tid >> 6;
  const int lane = tid & 63;
  const int u = lane & 15;           // t-column
  const int lgrp = lane >> 4;

  // stage x (bf16, masked)
  for (int idx = tid; idx < CC * 16; idx += 512) {
    int t = idx / CC, c = idx - t * CC;
    float v = (t < d) ? mel[(size_t)(b * Mmel + st + t) * CC + c] : 0.f;
    xs[c][t] = f2bf(v);
  }

  // load A-frags (register resident, shared by all c)
  bf16x8 a1[16], a2[8];
#pragma unroll
  for (int nt = 0; nt < 16; nt++)
    a1[nt] = *(const bf16x8*)&wpc[nt * 512 + lane * 8];
#pragma unroll
  for (int ks = 0; ks < 8; ks++)
    a2[ks] = *(const bf16x8*)&wpc[8192 + ks * 512 + lane * 8];

  const float g2 = g2v[0] * rsqrtf(1.f + EPSV);
  const float be2 = be2v[0];
  const bool urow = (u < d);
  __syncthreads();

#pragma unroll 1
  for (int ci = 0; ci < 10; ci++) {
    const int c = wv * 10 + ci;
    // ---- build B1 frag: B1[k][u] = x[c][u+k-4] ----
    unsigned bw[4];
#pragma unroll
    for (int m = 0; m < 4; m++) {
      unsigned lo, hi;
#pragma unroll
      for (int half = 0; half < 2; half++) {
        int j = 2 * m + half;
        int k = lgrp * 8 + j;
        int idx = u + k - PP;
        int tc = min(max(idx, 0), 15);
        ushort xv = xs[c][tc];
        ushort vv = (k < KK && idx >= 0 && idx < 16) ? xv
                    : ((k == KK) ? (ushort)0x3F80 : (ushort)0);
        if (half == 0) lo = vv; else hi = vv;
      }
      bw[m] = lo | (hi << 16);
    }
    int4 bi4 = make_int4(bw[0], bw[1], bw[2], bw[3]);
    bf16x8 b1 = *(bf16x8*)&bi4;

    // ---- conv1 MFMAs: acc1[nt] = Y[h=nt*16+lgrp*4+r][u] ----
    f32x4 acc1[16];
#pragma unroll
    for (int nt = 0; nt < 16; nt++) {
      f32x4 z = {0.f, 0.f, 0.f, 0.f};
      acc1[nt] = __builtin_amdgcn_mfma_f32_16x16x32_bf16(a1[nt], b1, z, 0, 0, 0);
    }

    // ---- relu + mask + pack to bf16 pairs ----
    unsigned P0[16], P1[16];
#pragma unroll
    for (int nt = 0; nt < 16; nt++) {
      float y0 = urow ? fmaxf(acc1[nt][0], 0.f) : 0.f;
      float y1 = urow ? fmaxf(acc1[nt][1], 0.f) : 0.f;
      float y2 = urow ? fmaxf(acc1[nt][2], 0.f) : 0.f;
      float y3 = urow ? fmaxf(acc1[nt][3], 0.f) : 0.f;
      P0[nt] = (unsigned)__bfloat16_as_ushort(__float2bfloat16(y0)) |
               ((unsigned)__bfloat16_as_ushort(__float2bfloat16(y1)) << 16);
      P1[nt] = (unsigned)__bfloat16_as_ushort(__float2bfloat16(y2)) |
               ((unsigned)__bfloat16_as_ushort(__float2bfloat16(y3)) << 16);
    }

    // ---- conv2: shuffle-transpose B2 frags, 8 K-steps ----
    const int hi2 = lgrp >> 1;
    const int s0 = u + 16 * ((lgrp & 1) * 2);
    const int s1 = s0 + 16;
    f32x4 accQ = {0.f, 0.f, 0.f, 0.f};
#pragma unroll
    for (int ks = 0; ks < 8; ks++) {
      int v00 = __shfl((int)P0[2 * ks], s0, 64);
      int v10 = __shfl((int)P0[2 * ks + 1], s0, 64);
      unsigned q0 = hi2 ? v10 : v00;
      int v01 = __shfl((int)P1[2 * ks], s0, 64);
      int v11 = __shfl((int)P1[2 * ks + 1], s0, 64);
      unsigned q1 = hi2 ? v11 : v01;
      int v02 = __shfl((int)P0[2 * ks], s1, 64);
      int v12 = __shfl((int)P0[2 * ks + 1], s1, 64);
      unsigned q2 = hi2 ? v12 : v02;
      int v03 = __shfl((int)P1[2 * ks], s1, 64);
      int v13 = __shfl((int)P1[2 * ks + 1], s1, 64);
      unsigned q3 = hi2 ? v13 : v03;
      int4 b2i = make_int4(q0, q1, q2, q3);
      bf16x8 b2 = *(bf16x8*)&b2i;
      accQ = __builtin_amdgcn_mfma_f32_16x16x32_bf16(a2[ks], b2, accQ, 0, 0, 0);
    }

    // ---- Q gather: Q[u] = sum_k Z[k][u+k-4] ----
    float Q = 0.f;
#pragma unroll
    for (int k = 0; k < KK; k++) {
      int idx = u + k - PP;
      float zv = __shfl(accQ[k & 3], (idx & 15) + 16 * (k >> 2), 64);
      Q += (idx >= 0 && idx < 16) ? zv : 0.f;
    }
    float qf = urow ? fmaxf(Q * g2 + be2, 0.f) : 0.f;
    if (lgrp == 0) xgs[u][c] = qf;
  }
  __syncthreads();

  // coalesced store
  for (int idx = tid; idx < 16 * CC; idx += 512) {
    int t = idx / CC, c = idx - t * CC;
    xg[(size_t)(seg * TT + t) * CC + c] = xgs[t][c];
  }
}

// ---------------- x-gate GEMM: G[8192][1536] = xg[8192][80] @ Wcat^T + b ------
__global__ __launch_bounds__(256) void k_xgate(
    const float* __restrict__ xg, const float* __restrict__ wihf,
    const float* __restrict__ wihb, const float* __restrict__ bihf,
    const float* __restrict__ bihb, float* __restrict__ G) {
  __shared__ float As[CC][68];
  __shared__ float Bs[CC][68];
  const int m0 = blockIdx.x * 64;
  const int n0 = blockIdx.y * 64;
  const int tid = threadIdx.x;
  {
    int row = tid >> 2, kq = tid & 3;
    const float4* src = (const float4*)(xg + (size_t)(m0 + row) * CC);
#pragma unroll
    for (int j = 0; j < 5; j++) {
      float4 v = src[kq * 5 + j];
      int k = (kq * 5 + j) * 4;
      As[k + 0][row] = v.x; As[k + 1][row] = v.y;
      As[k + 2][row] = v.z; As[k + 3][row] = v.w;
    }
    int n = n0 + row;
    const float* bsrc = (n < G3) ? (wihf + (size_t)n * CC)
                                 : (wihb + (size_t)(n - G3) * CC);
    const float4* bs4 = (const float4*)bsrc;
#pragma unroll
    for (int j = 0; j < 5; j++) {
      float4 v = bs4[kq * 5 + j];
      int k = (kq * 5 + j) * 4;
      Bs[k + 0][row] = v.x; Bs[k + 1][row] = v.y;
      Bs[k + 2][row] = v.z; Bs[k + 3][row] = v.w;
    }
  }
  __syncthreads();
  const int tx = tid & 15, ty = tid >> 4;
  float acc[4][4] = {};
#pragma unroll 4
  for (int k = 0; k < CC; k++) {
    float4 a = *(const float4*)&As[k][tx * 4];
    float4 bq = *(const float4*)&Bs[k][ty * 4];
    float av[4] = {a.x, a.y, a.z, a.w};
    float bv[4] = {bq.x, bq.y, bq.z, bq.w};
#pragma unroll
    for (int i = 0; i < 4; i++)
#pragma unroll
      for (int j = 0; j < 4; j++) acc[i][j] += av[i] * bv[j];
  }
  float bb[4];
#pragma unroll
  for (int j = 0; j < 4; j++) {
    int n = n0 + ty * 4 + j;
    bb[j] = (n < G3) ? bihf[n] : bihb[n - G3];
  }
#pragma unroll
  for (int i = 0; i < 4; i++) {
    int m = m0 + tx * 4 + i;
    float4 o;
    o.x = acc[i][0] + bb[0];
    o.y = acc[i][1] + bb[1];
    o.z = acc[i][2] + bb[2];
    o.w = acc[i][3] + bb[3];
    *(float4*)&G[(size_t)m * 1536 + n0 + ty * 4] = o;
  }
}

// ---------------- pack whh (both dirs) into bf16 MFMA-fragment order ----------
__global__ __launch_bounds__(256) void k_wpack(const float* __restrict__ whhf,
                                               const float* __restrict__ whhb,
                                               ushort* __restrict__ wp) {
  int tid = blockIdx.x * 256 + threadIdx.x;   // 0..393215
  int r = tid;
  int j = r & 7; r >>= 3;
  int lane = r & 63; r >>= 6;
  int ks = r & 7; r >>= 3;
  int tau = r % 6; r /= 6;
  int wv = r & 7; r >>= 3;
  int dir = r;
  int gate = tau >> 1, a = tau & 1;
  int n = gate * 256 + wv * 32 + a * 16 + (lane & 15);
  int k = ks * 32 + (lane >> 4) * 8 + j;
  float v = (dir ? whhb : whhf)[(size_t)n * HH + k];
  wp[tid] = f2bf(v);
}

// ---------------- fused bidirectional GRU: weights register/LDS-resident ------
__global__ __launch_bounds__(512, 2) void k_gru(
    const float* __restrict__ G, const ushort* __restrict__ wp,
    const float* __restrict__ bhhf, const float* __restrict__ bhhb,
    const int* __restrict__ dur, const int* __restrict__ perm,
    float* __restrict__ out) {
  __shared__ short h_lds[2][16 * HSTR];     // double-buffered bf16 h
  __shared__ ushort wlds[8 * 2 * 8 * 512];  // 131072 B: tau=4,5 frags per wave
  __shared__ int seg_s[16], d_s[16];

  const int tid = threadIdx.x;
  const int bi = blockIdx.x;           // 0..63
  const int dir = bi >> 5;
  const int grp = bi & 31;
  const int wv = tid >> 6;
  const int lane = tid & 63;
  const int lrow = lane & 15;
  const int lgrp = lane >> 4;

  if (tid < 16) {
    int seg = perm[grp * 16 + tid];
    seg_s[tid] = seg;
    d_s[tid] = dur[seg];
  }
  for (int idx = tid; idx < 2 * 16 * HSTR; idx += 512)
    ((short*)h_lds)[idx] = 0;

  const ushort* wb = wp + (size_t)(dir * 8 + wv) * 6 * 8 * 512 + lane * 8;
  bf16x8 wreg[4][8];
#pragma unroll
  for (int tau = 0; tau < 4; tau++)
#pragma unroll
    for (int ks = 0; ks < 8; ks++)
      wreg[tau][ks] = *(const bf16x8*)&wb[(tau * 8 + ks) * 512];
#pragma unroll
  for (int tt2 = 0; tt2 < 2; tt2++)
#pragma unroll
    for (int ks = 0; ks < 8; ks++) {
      bf16x8 v = *(const bf16x8*)&wb[((4 + tt2) * 8 + ks) * 512];
      *(bf16x8*)&wlds[((wv * 2 + tt2) * 8 + ks) * 512 + lane * 8] = v;
    }
  __syncthreads();

  int d4[4], seg4[4];
#pragma unroll
  for (int r = 0; r < 4; r++) {
    d4[r] = d_s[lgrp * 4 + r];
    seg4[r] = seg_s[lgrp * 4 + r];
  }
  int dmax = 0;
#pragma unroll
  for (int q = 0; q < 16; q++) dmax = max(dmax, d_s[q]);

  const int i0 = wv * 32 + lrow;
  const float* bh = dir ? bhhb : bhhf;
  float bias[3][2];
#pragma unroll
  for (int g = 0; g < 3; g++)
#pragma unroll
    for (int a = 0; a < 2; a++) bias[g][a] = bh[g * 256 + i0 + 16 * a];

  float h[4][2] = {};

  for (int t = 0; t < dmax; t++) {
    const int cur = t & 1;
    float gx[4][3][2];
#pragma unroll
    for (int r = 0; r < 4; r++) {
      if (t < d4[r]) {
        int ts = dir ? (d4[r] - 1 - t) : t;
        const float* grow = G + (size_t)(seg4[r] * TT + ts) * 1536 + dir * G3;
#pragma unroll
        for (int g = 0; g < 3; g++)
#pragma unroll
          for (int a = 0; a < 2; a++) gx[r][g][a] = grow[g * 256 + i0 + 16 * a];
      }
    }
    f32x4 acc[6];
#pragma unroll
    for (int tau = 0; tau < 6; tau++) acc[tau] = (f32x4){0.f, 0.f, 0.f, 0.f};
#pragma unroll
    for (int ks = 0; ks < 8; ks++) {
      bf16x8 av = *(const bf16x8*)&h_lds[cur][lrow * HSTR + ks * 32 + lgrp * 8];
#pragma unroll
      for (int tau = 0; tau < 4; tau++)
        acc[tau] = __builtin_amdgcn_mfma_f32_16x16x32_bf16(av, wreg[tau][ks],
                                                           acc[tau], 0, 0, 0);
#pragma unroll
      for (int tt2 = 0; tt2 < 2; tt2++) {
        bf16x8 wf = *(const bf16x8*)&wlds[((wv * 2 + tt2) * 8 + ks) * 512 + lane * 8];
        acc[4 + tt2] = __builtin_amdgcn_mfma_f32_16x16x32_bf16(av, wf,
                                                               acc[4 + tt2], 0, 0, 0);
      }
    }
#pragma unroll
    for (int r = 0; r < 4; r++) {
      if (t < d4[r]) {
#pragma unroll
        for (int a = 0; a < 2; a++) {
          float rr = fsig(gx[r][0][a] + acc[a][r] + bias[0][a]);
          float zz = fsig(gx[r][1][a] + acc[2 + a][r] + bias[1][a]);
          float nn = ftanh(gx[r][2][a] + rr * (acc[4 + a][r] + bias[2][a]));
          h[r][a] = (1.f - zz) * nn + zz * h[r][a];
          h_lds[cur ^ 1][(lgrp * 4 + r) * HSTR + i0 + 16 * a] = (short)f2bf(h[r][a]);
        }
      }
    }
    __syncthreads();
  }

#pragma unroll
  for (int r = 0; r < 4; r++)
#pragma unroll
    for (int a = 0; a < 2; a++)
      out[(size_t)seg4[r] * 512 + dir * 256 + i0 + 16 * a] = h[r][a];
}

extern "C" void kernel_launch(void* const* d_in, const int* in_sizes, int n_in,
                              void* d_out, int out_size, void* d_ws, size_t ws_size,
                              hipStream_t stream) {
  const float* mel = (const float*)d_in[0];
  const int Mmel = in_sizes[0] / (BB * CC);
  const int* duration = (const int*)d_in[2];
  const int* src_len = (const int*)d_in[3];
  const float* conv1_w = (const float*)d_in[5];
  const float* bn1_g = (const float*)d_in[6];
  const float* bn1_b = (const float*)d_in[7];
  const float* conv2_w = (const float*)d_in[8];
  const float* bn2_g = (const float*)d_in[9];
  const float* bn2_b = (const float*)d_in[10];
  const float* w_ih_f = (const float*)d_in[11];
  const float* w_hh_f = (const float*)d_in[12];
  const float* b_ih_f = (const float*)d_in[13];
  const float* b_hh_f = (const float*)d_in[14];
  const float* w_ih_b = (const float*)d_in[15];
  const float* w_hh_b = (const float*)d_in[16];
  const float* b_ih_b = (const float*)d_in[17];
  const float* b_hh_b = (const float*)d_in[18];

  char* w = (char*)d_ws;
  int* starts = (int*)w;            w += 512 * sizeof(int);
  int* dur = (int*)w;               w += 512 * sizeof(int);
  int* perm = (int*)w;              w += 512 * sizeof(int);
  w += 512 * sizeof(int);           // pad
  float* xg = (float*)w;            w += (size_t)NSEG * TT * CC * sizeof(float);     // 2.62 MB
  float* G = (float*)w;             w += (size_t)NSEG * TT * 1536 * sizeof(float);   // 50.3 MB
  ushort* wp = (ushort*)w;          w += (size_t)2 * 8 * 6 * 8 * 512 * sizeof(ushort); // 786 KB
  ushort* wpc = (ushort*)w;         w += (size_t)12288 * sizeof(ushort);             // 24.6 KB
  (void)ws_size; (void)n_in; (void)out_size;

  k_prep<<<1, 512, 0, stream>>>(duration, src_len, starts, dur, perm);
  k_wpack<<<1536, 256, 0, stream>>>(w_hh_f, w_hh_b, wp);
  k_wpackc<<<48, 256, 0, stream>>>(conv1_w, bn1_g, bn1_b, conv2_w, wpc);
  k_conv<<<NSEG, 512, 0, stream>>>(mel, starts, dur, wpc, bn2_g, bn2_b, xg, Mmel);
  k_xgate<<<dim3(128, 24), 256, 0, stream>>>(xg, w_ih_f, w_ih_b, b_ih_f, b_ih_b, G);
  k_gru<<<64, 512, 0, stream>>>(G, wp, b_hh_f, b_hh_b, dur, perm, (float*)d_out);
}

// Round 8
// 140.199 us; speedup vs baseline: 5.6766x; 1.0161x over previous
//
#include <hip/hip_runtime.h>
#include <hip/hip_bf16.h>
#include <math.h>

// Problem constants
#define BB 4
#define SS 128
#define CC 80          // C_MEL
#define HH 256         // D_MODEL
#define KK 9
#define PP 4           // (K-1)/2
#define TT 16          // MAX_DUR
#define NSEG 512       // B*S
#define G3 768         // 3*H
#define EPSV 1e-5f

typedef short bf16x8 __attribute__((ext_vector_type(8)));
typedef float f32x4 __attribute__((ext_vector_type(4)));

#define HSTR 264       // h_lds row stride in bf16 elems (256 + 8 pad)

__device__ inline ushort f2bf(float f) {
  unsigned x = __float_as_uint(f);
  unsigned r = (x + 0x7FFF + ((x >> 16) & 1)) >> 16;  // RNE
  return (ushort)r;
}
__device__ inline float fsig(float x) { return 1.f / (1.f + __expf(-x)); }
__device__ inline float ftanh(float x) {
  float e = __expf(2.f * x);
  return 1.f - 2.f / (e + 1.f);
}

// ---------------- prep: starts, durations, duration-sorted seg permutation ----
__global__ __launch_bounds__(512) void k_prep(const int* __restrict__ duration,
                                              const int* __restrict__ srclen,
                                              int* __restrict__ starts,
                                              int* __restrict__ dur,
                                              int* __restrict__ perm) {
  __shared__ int ds[512];
  __shared__ int hist[17];
  __shared__ int base[17];
  int tid = threadIdx.x;               // 0..511
  int b = tid >> 7, s = tid & 127;
  int v = (s < srclen[b]) ? duration[b * SS + s] : 0;
  ds[tid] = v;
  if (tid < 17) hist[tid] = 0;
  __syncthreads();
  int run = 0;
  for (int s2 = b * 128; s2 < tid; ++s2) run += ds[s2];
  starts[tid] = run;
  dur[tid] = v;
  atomicAdd(&hist[v], 1);
  __syncthreads();
  if (tid == 0) {
    int acc = 0;
    for (int q = 0; q < 17; q++) { base[q] = acc; acc += hist[q]; }
  }
  __syncthreads();
  int rank = atomicAdd(&base[v], 1);
  perm[rank] = tid;
}

// ---------------- pack conv weights into MFMA fragment order (bf16) ----------
// A1 frags (conv1, M=h): wpc[nt*512 + lane*8 + j]:
//   h = nt*16 + (lane&15), k = (lane>>4)*8 + j
//   val = k<9 ? w1[k][h]*g1'[h] : (k==9 ? be1[h] : 0)
// A2 frags (conv2, M=k): wpc[8192 + ks*512 + lane*8 + j]:
//   k = lane&15, h = ks*32 + (lane>>4)*8 + j; val = k<9 ? w2[k][h] : 0
__global__ __launch_bounds__(256) void k_wpackc(const float* __restrict__ w1,
                                                const float* __restrict__ g1v,
                                                const float* __restrict__ be1v,
                                                const float* __restrict__ w2,
                                                ushort* __restrict__ wpc) {
  int tid = blockIdx.x * 256 + threadIdx.x;   // 0..12287
  if (tid < 8192) {
    int nt = tid >> 9;
    int lane = (tid >> 3) & 63;
    int j = tid & 7;
    int h = nt * 16 + (lane & 15);
    int k = (lane >> 4) * 8 + j;
    float val = 0.f;
    if (k < KK) val = w1[k * HH + h] * (g1v[h] * rsqrtf(1.f + EPSV));
    else if (k == KK) val = be1v[h];
    wpc[tid] = f2bf(val);
  } else if (tid < 12288) {
    int q = tid - 8192;
    int ks = q >> 9;
    int lane = (q >> 3) & 63;
    int j = q & 7;
    int k = lane & 15;
    int h = ks * 32 + (lane >> 4) * 8 + j;
    float val = (k < KK) ? w2[k * HH + h] : 0.f;
    wpc[tid] = f2bf(val);
  }
}

// ---------------- conv stack via chained MFMA: 1 block per segment ------------
// conv1: D1[h][u] = sum_k A1[h][k] B1[k][u]; B1 from zero-padded xs2 rows.
// relu+mask -> bf16 pack -> wave-private LDS transpose (yt), XOR swizzle
// applied to the WITHIN-ROW offset only (row stride 528 is not 64-aligned, so
// XORing the full address mixed cells across rows -> rounds 6/7 failure).
// conv2: Z[k][u] = sum_h w2[k][h] Y[h][u]; Q[u] = sum_k Z[k][u+k-4] via shfl.
__global__ __launch_bounds__(512, 2) void k_conv(
    const float* __restrict__ mel, const int* __restrict__ starts,
    const int* __restrict__ dur, const ushort* __restrict__ wpc,
    const float* __restrict__ g2v, const float* __restrict__ be2v,
    float* __restrict__ xg, int Mmel) {
  __shared__ __align__(16) ushort xs2[CC][32];      // 5 KB, rows zero-padded
  __shared__ __align__(16) ushort yt[8 * 16 * 264]; // 67.6 KB transpose scratch
  __shared__ __align__(16) float xgs[16][81];       // 5.2 KB staged output

  const int seg = blockIdx.x;
  const int b = seg >> 7;
  const int d = dur[seg];
  const int st = starts[seg];
  const int tid = threadIdx.x;
  const int wv = tid >> 6;
  const int lane = tid & 63;
  const int u = lane & 15;           // t-column
  const int lgrp = lane >> 4;

  // stage x: t-inner lane mapping -> conflict-free LDS writes
  for (int idx = tid; idx < CC * 16; idx += 512) {
    int c = idx >> 4, t = idx & 15;
    float v = (t < d) ? mel[(size_t)(b * Mmel + st + t) * CC + c] : 0.f;
    xs2[c][t + 4] = f2bf(v);
  }
  // zero the pad regions: p in [0,4) and [20,32)
  for (int idx = tid; idx < CC * 16; idx += 512) {
    int c = idx >> 4, q = idx & 15;
    int p = (q < 4) ? q : (q + 16);
    xs2[c][p] = 0;
  }

  // A-frags (compiler may rematerialize; L2-resident)
  bf16x8 a1[16], a2[8];
#pragma unroll
  for (int nt = 0; nt < 16; nt++)
    a1[nt] = *(const bf16x8*)&wpc[nt * 512 + lane * 8];
#pragma unroll
  for (int ks = 0; ks < 8; ks++)
    a2[ks] = *(const bf16x8*)&wpc[8192 + ks * 512 + lane * 8];

  const float g2 = g2v[0] * rsqrtf(1.f + EPSV);
  const float be2 = be2v[0];
  const bool urow = (u < d);
  const unsigned umask = urow ? 0xFFFFFFFFu : 0u;
  char* ytp = (char*)yt + wv * (16 * 264 * 2);
  const int swz = (u & 3) << 4;
  __syncthreads();

#pragma unroll 1
  for (int ci = 0; ci < 10; ci++) {
    const int c = wv * 10 + ci;
    // ---- build B1 frag: elem j -> k=lgrp*8+j, val = xs2[c][u + k] ----
    unsigned bw0 = 0, bw1 = 0, bw2 = 0, bw3 = 0;
    if (lgrp == 0) {
      ushort e0 = xs2[c][u + 0], e1 = xs2[c][u + 1];
      ushort e2 = xs2[c][u + 2], e3 = xs2[c][u + 3];
      ushort e4 = xs2[c][u + 4], e5 = xs2[c][u + 5];
      ushort e6 = xs2[c][u + 6], e7 = xs2[c][u + 7];
      bw0 = (unsigned)e0 | ((unsigned)e1 << 16);
      bw1 = (unsigned)e2 | ((unsigned)e3 << 16);
      bw2 = (unsigned)e4 | ((unsigned)e5 << 16);
      bw3 = (unsigned)e6 | ((unsigned)e7 << 16);
    } else if (lgrp == 1) {
      ushort e0 = xs2[c][u + 8];                  // k=8
      bw0 = (unsigned)e0 | (0x3F80u << 16);       // k=9: bias column = 1.0
    }
    int4 bi4 = make_int4(bw0, bw1, bw2, bw3);
    bf16x8 b1 = *(bf16x8*)&bi4;

    // ---- conv1 MFMAs: acc1[nt] = Y[h=nt*16+lgrp*4+r][u] ----
    f32x4 acc1[16];
#pragma unroll
    for (int nt = 0; nt < 16; nt++) {
      f32x4 z = {0.f, 0.f, 0.f, 0.f};
      acc1[nt] = __builtin_amdgcn_mfma_f32_16x16x32_bf16(a1[nt], b1, z, 0, 0, 0);
    }

    // ---- relu + pack to bf16 + mask, write to yt (within-row swizzle) ----
#pragma unroll
    for (int nt = 0; nt < 16; nt++) {
      float y0 = fmaxf(acc1[nt][0], 0.f);
      float y1 = fmaxf(acc1[nt][1], 0.f);
      float y2 = fmaxf(acc1[nt][2], 0.f);
      float y3 = fmaxf(acc1[nt][3], 0.f);
      unsigned p0 = ((unsigned)__bfloat16_as_ushort(__float2bfloat16(y0)) |
                     ((unsigned)__bfloat16_as_ushort(__float2bfloat16(y1)) << 16)) & umask;
      unsigned p1 = ((unsigned)__bfloat16_as_ushort(__float2bfloat16(y2)) |
                     ((unsigned)__bfloat16_as_ushort(__float2bfloat16(y3)) << 16)) & umask;
      int wbyte = u * 528 + ((nt * 32 + lgrp * 8) ^ swz);   // swizzle in-row only
      *(uint2*)(ytp + wbyte) = make_uint2(p0, p1);
    }
    asm volatile("" ::: "memory");   // keep ds_writes before the ds_reads

    // ---- conv2: read B2 frags from yt (uint2 pairs), 8 K-steps ----
    f32x4 accQ = {0.f, 0.f, 0.f, 0.f};
#pragma unroll
    for (int ks = 0; ks < 8; ks++) {
      int rbyte = u * 528 + ((ks * 64 + lgrp * 16) ^ swz);  // swizzle in-row only
      uint2 lo = *(const uint2*)(ytp + rbyte);
      uint2 hi = *(const uint2*)(ytp + rbyte + 8);
      int4 b2i = make_int4(lo.x, lo.y, hi.x, hi.y);
      bf16x8 b2 = *(bf16x8*)&b2i;
      accQ = __builtin_amdgcn_mfma_f32_16x16x32_bf16(a2[ks], b2, accQ, 0, 0, 0);
    }
    asm volatile("" ::: "memory");   // keep ds_reads before next iter's writes

    // ---- Q gather: Q[u] = sum_k Z[k][u+k-4] ----
    float Q = 0.f;
#pragma unroll
    for (int k = 0; k < KK; k++) {
      int idx = u + k - PP;
      float zv = __shfl(accQ[k & 3], (idx & 15) + 16 * (k >> 2), 64);
      Q += (idx >= 0 && idx < 16) ? zv : 0.f;
    }
    float qf = urow ? fmaxf(Q * g2 + be2, 0.f) : 0.f;
    if (lgrp == 0) xgs[u][c] = qf;
  }
  __syncthreads();

  // coalesced store
  for (int idx = tid; idx < 16 * CC; idx += 512) {
    int t = idx / CC, c = idx - t * CC;
    xg[(size_t)(seg * TT + t) * CC + c] = xgs[t][c];
  }
}

// ---------------- x-gate GEMM: G[8192][1536] = xg[8192][80] @ Wcat^T + b ------
__global__ __launch_bounds__(256) void k_xgate(
    const float* __restrict__ xg, const float* __restrict__ wihf,
    const float* __restrict__ wihb, const float* __restrict__ bihf,
    const float* __restrict__ bihb, float* __restrict__ G) {
  __shared__ float As[CC][68];
  __shared__ float Bs[CC][68];
  const int m0 = blockIdx.x * 64;
  const int n0 = blockIdx.y * 64;
  const int tid = threadIdx.x;
  {
    int row = tid >> 2, kq = tid & 3;
    const float4* src = (const float4*)(xg + (size_t)(m0 + row) * CC);
#pragma unroll
    for (int j = 0; j < 5; j++) {
      float4 v = src[kq * 5 + j];
      int k = (kq * 5 + j) * 4;
      As[k + 0][row] = v.x; As[k + 1][row] = v.y;
      As[k + 2][row] = v.z; As[k + 3][row] = v.w;
    }
    int n = n0 + row;
    const float* bsrc = (n < G3) ? (wihf + (size_t)n * CC)
                                 : (wihb + (size_t)(n - G3) * CC);
    const float4* bs4 = (const float4*)bsrc;
#pragma unroll
    for (int j = 0; j < 5; j++) {
      float4 v = bs4[kq * 5 + j];
      int k = (kq * 5 + j) * 4;
      Bs[k + 0][row] = v.x; Bs[k + 1][row] = v.y;
      Bs[k + 2][row] = v.z; Bs[k + 3][row] = v.w;
    }
  }
  __syncthreads();
  const int tx = tid & 15, ty = tid >> 4;
  float acc[4][4] = {};
#pragma unroll 4
  for (int k = 0; k < CC; k++) {
    float4 a = *(const float4*)&As[k][tx * 4];
    float4 bq = *(const float4*)&Bs[k][ty * 4];
    float av[4] = {a.x, a.y, a.z, a.w};
    float bv[4] = {bq.x, bq.y, bq.z, bq.w};
#pragma unroll
    for (int i = 0; i < 4; i++)
#pragma unroll
      for (int j = 0; j < 4; j++) acc[i][j] += av[i] * bv[j];
  }
  float bb[4];
#pragma unroll
  for (int j = 0; j < 4; j++) {
    int n = n0 + ty * 4 + j;
    bb[j] = (n < G3) ? bihf[n] : bihb[n - G3];
  }
#pragma unroll
  for (int i = 0; i < 4; i++) {
    int m = m0 + tx * 4 + i;
    float4 o;
    o.x = acc[i][0] + bb[0];
    o.y = acc[i][1] + bb[1];
    o.z = acc[i][2] + bb[2];
    o.w = acc[i][3] + bb[3];
    *(float4*)&G[(size_t)m * 1536 + n0 + ty * 4] = o;
  }
}

// ---------------- pack whh (both dirs) into bf16 MFMA-fragment order ----------
__global__ __launch_bounds__(256) void k_wpack(const float* __restrict__ whhf,
                                               const float* __restrict__ whhb,
                                               ushort* __restrict__ wp) {
  int tid = blockIdx.x * 256 + threadIdx.x;   // 0..393215
  int r = tid;
  int j = r & 7; r >>= 3;
  int lane = r & 63; r >>= 6;
  int ks = r & 7; r >>= 3;
  int tau = r % 6; r /= 6;
  int wv = r & 7; r >>= 3;
  int dir = r;
  int gate = tau >> 1, a = tau & 1;
  int n = gate * 256 + wv * 32 + a * 16 + (lane & 15);
  int k = ks * 32 + (lane >> 4) * 8 + j;
  float v = (dir ? whhb : whhf)[(size_t)n * HH + k];
  wp[tid] = f2bf(v);
}

// ---------------- fused bidirectional GRU: weights register/LDS-resident ------
__global__ __launch_bounds__(512, 2) void k_gru(
    const float* __restrict__ G, const ushort* __restrict__ wp,
    const float* __restrict__ bhhf, const float* __restrict__ bhhb,
    const int* __restrict__ dur, const int* __restrict__ perm,
    float* __restrict__ out) {
  __shared__ short h_lds[2][16 * HSTR];     // double-buffered bf16 h
  __shared__ ushort wlds[8 * 2 * 8 * 512];  // 131072 B: tau=4,5 frags per wave
  __shared__ int seg_s[16], d_s[16];

  const int tid = threadIdx.x;
  const int bi = blockIdx.x;           // 0..63
  const int dir = bi >> 5;
  const int grp = bi & 31;
  const int wv = tid >> 6;
  const int lane = tid & 63;
  const int lrow = lane & 15;
  const int lgrp = lane >> 4;

  if (tid < 16) {
    int seg = perm[grp * 16 + tid];
    seg_s[tid] = seg;
    d_s[tid] = dur[seg];
  }
  for (int idx = tid; idx < 2 * 16 * HSTR; idx += 512)
    ((short*)h_lds)[idx] = 0;

  const ushort* wb = wp + (size_t)(dir * 8 + wv) * 6 * 8 * 512 + lane * 8;
  bf16x8 wreg[4][8];
#pragma unroll
  for (int tau = 0; tau < 4; tau++)
#pragma unroll
    for (int ks = 0; ks < 8; ks++)
      wreg[tau][ks] = *(const bf16x8*)&wb[(tau * 8 + ks) * 512];
#pragma unroll
  for (int tt2 = 0; tt2 < 2; tt2++)
#pragma unroll
    for (int ks = 0; ks < 8; ks++) {
      bf16x8 v = *(const bf16x8*)&wb[((4 + tt2) * 8 + ks) * 512];
      *(bf16x8*)&wlds[((wv * 2 + tt2) * 8 + ks) * 512 + lane * 8] = v;
    }
  __syncthreads();

  int d4[4], seg4[4];
#pragma unroll
  for (int r = 0; r < 4; r++) {
    d4[r] = d_s[lgrp * 4 + r];
    seg4[r] = seg_s[lgrp * 4 + r];
  }
  int dmax = 0;
#pragma unroll
  for (int q = 0; q < 16; q++) dmax = max(dmax, d_s[q]);

  const int i0 = wv * 32 + lrow;
  const float* bh = dir ? bhhb : bhhf;
  float bias[3][2];
#pragma unroll
  for (int g = 0; g < 3; g++)
#pragma unroll
    for (int a = 0; a < 2; a++) bias[g][a] = bh[g * 256 + i0 + 16 * a];

  float h[4][2] = {};

  for (int t = 0; t < dmax; t++) {
    const int cur = t & 1;
    float gx[4][3][2];
#pragma unroll
    for (int r = 0; r < 4; r++) {
      if (t < d4[r]) {
        int ts = dir ? (d4[r] - 1 - t) : t;
        const float* grow = G + (size_t)(seg4[r] * TT + ts) * 1536 + dir * G3;
#pragma unroll
        for (int g = 0; g < 3; g++)
#pragma unroll
          for (int a = 0; a < 2; a++) gx[r][g][a] = grow[g * 256 + i0 + 16 * a];
      }
    }
    f32x4 acc[6];
#pragma unroll
    for (int tau = 0; tau < 6; tau++) acc[tau] = (f32x4){0.f, 0.f, 0.f, 0.f};
#pragma unroll
    for (int ks = 0; ks < 8; ks++) {
      bf16x8 av = *(const bf16x8*)&h_lds[cur][lrow * HSTR + ks * 32 + lgrp * 8];
#pragma unroll
      for (int tau = 0; tau < 4; tau++)
        acc[tau] = __builtin_amdgcn_mfma_f32_16x16x32_bf16(av, wreg[tau][ks],
                                                           acc[tau], 0, 0, 0);
#pragma unroll
      for (int tt2 = 0; tt2 < 2; tt2++) {
        bf16x8 wf = *(const bf16x8*)&wlds[((wv * 2 + tt2) * 8 + ks) * 512 + lane * 8];
        acc[4 + tt2] = __builtin_amdgcn_mfma_f32_16x16x32_bf16(av, wf,
                                                               acc[4 + tt2], 0, 0, 0);
      }
    }
#pragma unroll
    for (int r = 0; r < 4; r++) {
      if (t < d4[r]) {
#pragma unroll
        for (int a = 0; a < 2; a++) {
          float rr = fsig(gx[r][0][a] + acc[a][r] + bias[0][a]);
          float zz = fsig(gx[r][1][a] + acc[2 + a][r] + bias[1][a]);
          float nn = ftanh(gx[r][2][a] + rr * (acc[4 + a][r] + bias[2][a]));
          h[r][a] = (1.f - zz) * nn + zz * h[r][a];
          h_lds[cur ^ 1][(lgrp * 4 + r) * HSTR + i0 + 16 * a] = (short)f2bf(h[r][a]);
        }
      }
    }
    __syncthreads();
  }

#pragma unroll
  for (int r = 0; r < 4; r++)
#pragma unroll
    for (int a = 0; a < 2; a++)
      out[(size_t)seg4[r] * 512 + dir * 256 + i0 + 16 * a] = h[r][a];
}

extern "C" void kernel_launch(void* const* d_in, const int* in_sizes, int n_in,
                              void* d_out, int out_size, void* d_ws, size_t ws_size,
                              hipStream_t stream) {
  const float* mel = (const float*)d_in[0];
  const int Mmel = in_sizes[0] / (BB * CC);
  const int* duration = (const int*)d_in[2];
  const int* src_len = (const int*)d_in[3];
  const float* conv1_w = (const float*)d_in[5];
  const float* bn1_g = (const float*)d_in[6];
  const float* bn1_b = (const float*)d_in[7];
  const float* conv2_w = (const float*)d_in[8];
  const float* bn2_g = (const float*)d_in[9];
  const float* bn2_b = (const float*)d_in[10];
  const float* w_ih_f = (const float*)d_in[11];
  const float* w_hh_f = (const float*)d_in[12];
  const float* b_ih_f = (const float*)d_in[13];
  const float* b_hh_f = (const float*)d_in[14];
  const float* w_ih_b = (const float*)d_in[15];
  const float* w_hh_b = (const float*)d_in[16];
  const float* b_ih_b = (const float*)d_in[17];
  const float* b_hh_b = (const float*)d_in[18];

  char* w = (char*)d_ws;
  int* starts = (int*)w;            w += 512 * sizeof(int);
  int* dur = (int*)w;               w += 512 * sizeof(int);
  int* perm = (int*)w;              w += 512 * sizeof(int);
  w += 512 * sizeof(int);           // pad
  float* xg = (float*)w;            w += (size_t)NSEG * TT * CC * sizeof(float);     // 2.62 MB
  float* G = (float*)w;             w += (size_t)NSEG * TT * 1536 * sizeof(float);   // 50.3 MB
  ushort* wp = (ushort*)w;          w += (size_t)2 * 8 * 6 * 8 * 512 * sizeof(ushort); // 786 KB
  ushort* wpc = (ushort*)w;         w += (size_t)12288 * sizeof(ushort);             // 24.6 KB
  (void)ws_size; (void)n_in; (void)out_size;

  k_prep<<<1, 512, 0, stream>>>(duration, src_len, starts, dur, perm);
  k_wpack<<<1536, 256, 0, stream>>>(w_hh_f, w_hh_b, wp);
  k_wpackc<<<48, 256, 0, stream>>>(conv1_w, bn1_g, bn1_b, conv2_w, wpc);
  k_conv<<<NSEG, 512, 0, stream>>>(mel, starts, dur, wpc, bn2_g, bn2_b, xg, Mmel);
  k_xgate<<<dim3(128, 24), 256, 0, stream>>>(xg, w_ih_f, w_ih_b, b_ih_f, b_ih_b, G);
  k_gru<<<64, 512, 0, stream>>>(G, wp, b_hh_f, b_hh_b, dur, perm, (float*)d_out);
}

// Round 10
// 138.278 us; speedup vs baseline: 5.7555x; 1.0139x over previous
//
#include <hip/hip_runtime.h>
#include <hip/hip_bf16.h>
#include <math.h>

// Problem constants
#define BB 4
#define SS 128
#define CC 80          // C_MEL
#define HH 256         // D_MODEL
#define KK 9
#define PP 4           // (K-1)/2
#define TT 16          // MAX_DUR
#define NSEG 512       // B*S
#define G3 768         // 3*H
#define EPSV 1e-5f

typedef short bf16x8 __attribute__((ext_vector_type(8)));
typedef float f32x4 __attribute__((ext_vector_type(4)));

#define HSTR 264       // h_lds row stride in bf16 elems (256 + 8 pad)

__device__ inline ushort f2bf(float f) {
  unsigned x = __float_as_uint(f);
  unsigned r = (x + 0x7FFF + ((x >> 16) & 1)) >> 16;  // RNE
  return (ushort)r;
}
__device__ inline float fsig(float x) { return 1.f / (1.f + __expf(-x)); }
__device__ inline float ftanh(float x) {
  float e = __expf(2.f * x);
  return 1.f - 2.f / (e + 1.f);
}

// ---------------- prep: starts, durations, duration-sorted seg permutation ----
__global__ __launch_bounds__(512) void k_prep(const int* __restrict__ duration,
                                              const int* __restrict__ srclen,
                                              int* __restrict__ starts,
                                              int* __restrict__ dur,
                                              int* __restrict__ perm) {
  __shared__ int ds[512];
  __shared__ int hist[17];
  __shared__ int base[17];
  int tid = threadIdx.x;               // 0..511
  int b = tid >> 7, s = tid & 127;
  int v = (s < srclen[b]) ? duration[b * SS + s] : 0;
  ds[tid] = v;
  if (tid < 17) hist[tid] = 0;
  __syncthreads();
  int run = 0;
  for (int s2 = b * 128; s2 < tid; ++s2) run += ds[s2];
  starts[tid] = run;
  dur[tid] = v;
  atomicAdd(&hist[v], 1);
  __syncthreads();
  if (tid == 0) {
    int acc = 0;
    for (int q = 0; q < 17; q++) { base[q] = acc; acc += hist[q]; }
  }
  __syncthreads();
  int rank = atomicAdd(&base[v], 1);
  perm[rank] = tid;
}

// ---------------- pack conv weights into MFMA fragment order (bf16) ----------
// A1 frags (conv1, M=h): wpc[nt*512 + lane*8 + j]:
//   h = nt*16 + (lane&15), k = (lane>>4)*8 + j
//   val = k<9 ? w1[k][h]*g1'[h] : (k==9 ? be1[h] : 0)
// B2 frags (conv2 swapped, N=tap, K=h): wpc[8192 + ks*512 + lane*8 + j]:
//   tap = lane&15, h = ks*32 + (lane>>4)*8 + j; val = tap<9 ? w2[tap][h] : 0
__global__ __launch_bounds__(256) void k_wpackc(const float* __restrict__ w1,
                                                const float* __restrict__ g1v,
                                                const float* __restrict__ be1v,
                                                const float* __restrict__ w2,
                                                ushort* __restrict__ wpc) {
  int tid = blockIdx.x * 256 + threadIdx.x;   // 0..12287
  if (tid < 8192) {
    int nt = tid >> 9;
    int lane = (tid >> 3) & 63;
    int j = tid & 7;
    int h = nt * 16 + (lane & 15);
    int k = (lane >> 4) * 8 + j;
    float val = 0.f;
    if (k < KK) val = w1[k * HH + h] * (g1v[h] * rsqrtf(1.f + EPSV));
    else if (k == KK) val = be1v[h];
    wpc[tid] = f2bf(val);
  } else if (tid < 12288) {
    int q = tid - 8192;
    int ks = q >> 9;
    int lane = (q >> 3) & 63;
    int j = q & 7;
    int k = lane & 15;
    int h = ks * 32 + (lane >> 4) * 8 + j;
    float val = (k < KK) ? w2[k * HH + h] : 0.f;
    wpc[tid] = f2bf(val);
  }
}

// ---------------- conv stack via chained MFMA: 1 block per segment ------------
// conv1: Y[h][u] = A1(w1*g1,+be1) x B1(x patches)   [16 MFMA, 2 halves of 8]
// pack Y to masked bf16 pairs P (per lane: 4 h at fixed u=lrow)
// conv2 SWAPPED: Z^T[u'][tap] = A2(Y^T) x B2(W2^T). A2 words pulled from the
// 2 lanes with the SAME lrow via DOUBLE-shuffle at FIXED indices + select by
// hi2=lgrp>>1 (round-4-verified pattern; single shfl with lane-dependent index
// pulls the SOURCE lane's index -> wrong value, the round-9 bug).
// Q[t] = sum_tap Z[tap][t+tap-4] via small padded zs staging.
__global__ __launch_bounds__(512, 4) void k_conv(
    const float* __restrict__ mel, const int* __restrict__ starts,
    const int* __restrict__ dur, const ushort* __restrict__ wpc,
    const float* __restrict__ g2v, const float* __restrict__ be2v,
    float* __restrict__ xg, int Mmel) {
  __shared__ __align__(16) ushort xs2[CC][32];   // 5 KB, rows zero-padded
  __shared__ __align__(16) ushort wlc[12288];    // 24.6 KB: wpc staged in LDS
  __shared__ __align__(16) float zs[8][16][18];  // 9.2 KB per-wave Z staging
  __shared__ __align__(16) float xgs[16][81];    // 5.2 KB staged output

  const int seg = blockIdx.x;
  const int b = seg >> 7;
  const int d = dur[seg];
  const int st = starts[seg];
  const int tid = threadIdx.x;
  const int wv = tid >> 6;
  const int lane = tid & 63;
  const int u = lane & 15;           // t-column (= lrow)
  const int lgrp = lane >> 4;
  const int hi2 = lgrp >> 1;

  // stage conv weights into LDS (uint4 copies)
  {
    const uint4* src = (const uint4*)wpc;
    uint4* dst = (uint4*)wlc;
    for (int i = tid; i < 1536; i += 512) dst[i] = src[i];
  }
  // stage x: t-inner lane mapping -> conflict-free LDS writes
  for (int idx = tid; idx < CC * 16; idx += 512) {
    int c = idx >> 4, t = idx & 15;
    float v = (t < d) ? mel[(size_t)(b * Mmel + st + t) * CC + c] : 0.f;
    xs2[c][t + 4] = f2bf(v);
  }
  // zero the pad regions: p in [0,4) and [20,32)
  for (int idx = tid; idx < CC * 16; idx += 512) {
    int c = idx >> 4, q = idx & 15;
    int p = (q < 4) ? q : (q + 16);
    xs2[c][p] = 0;
  }

  const float g2 = g2v[0] * rsqrtf(1.f + EPSV);
  const float be2 = be2v[0];
  const bool urow = (u < d);
  const unsigned umask = urow ? 0xFFFFFFFFu : 0u;
  // A2 shuffle sources: same lrow; src0 covers j=0..3, src1 covers j=4..7
  const int src0 = (((lane >> 4) & 1) << 5) + u;
  const int src1 = src0 + 16;
  __syncthreads();

#pragma unroll 1
  for (int ci = 0; ci < 10; ci++) {
    const int c = wv * 10 + ci;
    // ---- build B1 frag: elem j -> k=lgrp*8+j, val = xs2[c][u + k] ----
    unsigned bw0 = 0, bw1 = 0, bw2 = 0, bw3 = 0;
    if (lgrp == 0) {
      ushort e0 = xs2[c][u + 0], e1 = xs2[c][u + 1];
      ushort e2 = xs2[c][u + 2], e3 = xs2[c][u + 3];
      ushort e4 = xs2[c][u + 4], e5 = xs2[c][u + 5];
      ushort e6 = xs2[c][u + 6], e7 = xs2[c][u + 7];
      bw0 = (unsigned)e0 | ((unsigned)e1 << 16);
      bw1 = (unsigned)e2 | ((unsigned)e3 << 16);
      bw2 = (unsigned)e4 | ((unsigned)e5 << 16);
      bw3 = (unsigned)e6 | ((unsigned)e7 << 16);
    } else if (lgrp == 1) {
      ushort e0 = xs2[c][u + 8];                  // k=8
      bw0 = (unsigned)e0 | (0x3F80u << 16);       // k=9: bias column = 1.0
    }
    int4 bi4 = make_int4(bw0, bw1, bw2, bw3);
    bf16x8 b1 = *(bf16x8*)&bi4;

    f32x4 accQ = {0.f, 0.f, 0.f, 0.f};

#pragma unroll
    for (int half = 0; half < 2; half++) {
      // ---- conv1: 8 MFMA -> Y[h][u] for h in [half*128, half*128+128) ----
      unsigned P0[8], P1[8];   // P0=pack(y_r0,y_r1), P1=pack(y_r2,y_r3), masked
#pragma unroll
      for (int i = 0; i < 8; i++) {
        int nt = half * 8 + i;
        bf16x8 a1 = *(const bf16x8*)&wlc[nt * 512 + lane * 8];
        f32x4 z = {0.f, 0.f, 0.f, 0.f};
        f32x4 y = __builtin_amdgcn_mfma_f32_16x16x32_bf16(a1, b1, z, 0, 0, 0);
        float y0 = fmaxf(y[0], 0.f), y1 = fmaxf(y[1], 0.f);
        float y2 = fmaxf(y[2], 0.f), y3 = fmaxf(y[3], 0.f);
        P0[i] = ((unsigned)__bfloat16_as_ushort(__float2bfloat16(y0)) |
                 ((unsigned)__bfloat16_as_ushort(__float2bfloat16(y1)) << 16)) & umask;
        P1[i] = ((unsigned)__bfloat16_as_ushort(__float2bfloat16(y2)) |
                 ((unsigned)__bfloat16_as_ushort(__float2bfloat16(y3)) << 16)) & umask;
      }
      // ---- conv2 swapped: A2 built by fixed-index double-shuffle + select ----
#pragma unroll
      for (int ks2 = 0; ks2 < 4; ks2++) {
        int ks = half * 4 + ks2;
        int v00 = __shfl((int)P0[2 * ks2], src0, 64);
        int v10 = __shfl((int)P0[2 * ks2 + 1], src0, 64);
        unsigned w0 = hi2 ? (unsigned)v10 : (unsigned)v00;   // (j0,j1)
        int v01 = __shfl((int)P1[2 * ks2], src0, 64);
        int v11 = __shfl((int)P1[2 * ks2 + 1], src0, 64);
        unsigned w1 = hi2 ? (unsigned)v11 : (unsigned)v01;   // (j2,j3)
        int v02 = __shfl((int)P0[2 * ks2], src1, 64);
        int v12 = __shfl((int)P0[2 * ks2 + 1], src1, 64);
        unsigned w2 = hi2 ? (unsigned)v12 : (unsigned)v02;   // (j4,j5)
        int v03 = __shfl((int)P1[2 * ks2], src1, 64);
        int v13 = __shfl((int)P1[2 * ks2 + 1], src1, 64);
        unsigned w3 = hi2 ? (unsigned)v13 : (unsigned)v03;   // (j6,j7)
        int4 ai4 = make_int4(w0, w1, w2, w3);
        bf16x8 a2 = *(bf16x8*)&ai4;
        bf16x8 b2 = *(const bf16x8*)&wlc[8192 + ks * 512 + lane * 8];
        accQ = __builtin_amdgcn_mfma_f32_16x16x32_bf16(a2, b2, accQ, 0, 0, 0);
      }
    }

    // ---- stage Z^T[u'=lgrp*4+r][tap=u] = accQ[r] ----
    if (u < KK) {
#pragma unroll
      for (int r = 0; r < 4; r++) zs[wv][lgrp * 4 + r][u] = accQ[r];
    }
    asm volatile("" ::: "memory");   // keep zs writes before reads

    // ---- Q gather: Q[t] = sum_tap zs[t+tap-4][tap] (16 lanes) ----
    if (lgrp == 0) {
      float Q = 0.f;
#pragma unroll
      for (int k = 0; k < KK; k++) {
        int idx = u + k - PP;
        if (idx >= 0 && idx < 16) Q += zs[wv][idx][k];
      }
      float qf = urow ? fmaxf(Q * g2 + be2, 0.f) : 0.f;
      xgs[u][c] = qf;
    }
    asm volatile("" ::: "memory");   // keep reads before next iter's writes
  }
  __syncthreads();

  // coalesced store
  for (int idx = tid; idx < 16 * CC; idx += 512) {
    int t = idx / CC, c = idx - t * CC;
    xg[(size_t)(seg * TT + t) * CC + c] = xgs[t][c];
  }
}

// ---------------- x-gate GEMM: G[8192][1536] = xg[8192][80] @ Wcat^T + b ------
__global__ __launch_bounds__(256) void k_xgate(
    const float* __restrict__ xg, const float* __restrict__ wihf,
    const float* __restrict__ wihb, const float* __restrict__ bihf,
    const float* __restrict__ bihb, float* __restrict__ G) {
  __shared__ float As[CC][68];
  __shared__ float Bs[CC][68];
  const int m0 = blockIdx.x * 64;
  const int n0 = blockIdx.y * 64;
  const int tid = threadIdx.x;
  {
    int row = tid >> 2, kq = tid & 3;
    const float4* src = (const float4*)(xg + (size_t)(m0 + row) * CC);
#pragma unroll
    for (int j = 0; j < 5; j++) {
      float4 v = src[kq * 5 + j];
      int k = (kq * 5 + j) * 4;
      As[k + 0][row] = v.x; As[k + 1][row] = v.y;
      As[k + 2][row] = v.z; As[k + 3][row] = v.w;
    }
    int n = n0 + row;
    const float* bsrc = (n < G3) ? (wihf + (size_t)n * CC)
                                 : (wihb + (size_t)(n - G3) * CC);
    const float4* bs4 = (const float4*)bsrc;
#pragma unroll
    for (int j = 0; j < 5; j++) {
      float4 v = bs4[kq * 5 + j];
      int k = (kq * 5 + j) * 4;
      Bs[k + 0][row] = v.x; Bs[k + 1][row] = v.y;
      Bs[k + 2][row] = v.z; Bs[k + 3][row] = v.w;
    }
  }
  __syncthreads();
  const int tx = tid & 15, ty = tid >> 4;
  float acc[4][4] = {};
#pragma unroll 4
  for (int k = 0; k < CC; k++) {
    float4 a = *(const float4*)&As[k][tx * 4];
    float4 bq = *(const float4*)&Bs[k][ty * 4];
    float av[4] = {a.x, a.y, a.z, a.w};
    float bv[4] = {bq.x, bq.y, bq.z, bq.w};
#pragma unroll
    for (int i = 0; i < 4; i++)
#pragma unroll
      for (int j = 0; j < 4; j++) acc[i][j] += av[i] * bv[j];
  }
  float bb[4];
#pragma unroll
  for (int j = 0; j < 4; j++) {
    int n = n0 + ty * 4 + j;
    bb[j] = (n < G3) ? bihf[n] : bihb[n - G3];
  }
#pragma unroll
  for (int i = 0; i < 4; i++) {
    int m = m0 + tx * 4 + i;
    float4 o;
    o.x = acc[i][0] + bb[0];
    o.y = acc[i][1] + bb[1];
    o.z = acc[i][2] + bb[2];
    o.w = acc[i][3] + bb[3];
    *(float4*)&G[(size_t)m * 1536 + n0 + ty * 4] = o;
  }
}

// ---------------- pack whh (both dirs) into bf16 MFMA-fragment order ----------
__global__ __launch_bounds__(256) void k_wpack(const float* __restrict__ whhf,
                                               const float* __restrict__ whhb,
                                               ushort* __restrict__ wp) {
  int tid = blockIdx.x * 256 + threadIdx.x;   // 0..393215
  int r = tid;
  int j = r & 7; r >>= 3;
  int lane = r & 63; r >>= 6;
  int ks = r & 7; r >>= 3;
  int tau = r % 6; r /= 6;
  int wv = r & 7; r >>= 3;
  int dir = r;
  int gate = tau >> 1, a = tau & 1;
  int n = gate * 256 + wv * 32 + a * 16 + (lane & 15);
  int k = ks * 32 + (lane >> 4) * 8 + j;
  float v = (dir ? whhb : whhf)[(size_t)n * HH + k];
  wp[tid] = f2bf(v);
}

// ---------------- fused bidirectional GRU: weights register/LDS-resident ------
__global__ __launch_bounds__(512, 2) void k_gru(
    const float* __restrict__ G, const ushort* __restrict__ wp,
    const float* __restrict__ bhhf, const float* __restrict__ bhhb,
    const int* __restrict__ dur, const int* __restrict__ perm,
    float* __restrict__ out) {
  __shared__ short h_lds[2][16 * HSTR];     // double-buffered bf16 h
  __shared__ ushort wlds[8 * 2 * 8 * 512];  // 131072 B: tau=4,5 frags per wave
  __shared__ int seg_s[16], d_s[16];

  const int tid = threadIdx.x;
  const int bi = blockIdx.x;           // 0..63
  const int dir = bi >> 5;
  const int grp = bi & 31;
  const int wv = tid >> 6;
  const int lane = tid & 63;
  const int lrow = lane & 15;
  const int lgrp = lane >> 4;

  if (tid < 16) {
    int seg = perm[grp * 16 + tid];
    seg_s[tid] = seg;
    d_s[tid] = dur[seg];
  }
  for (int idx = tid; idx < 2 * 16 * HSTR; idx += 512)
    ((short*)h_lds)[idx] = 0;

  const ushort* wb = wp + (size_t)(dir * 8 + wv) * 6 * 8 * 512 + lane * 8;
  bf16x8 wreg[4][8];
#pragma unroll
  for (int tau = 0; tau < 4; tau++)
#pragma unroll
    for (int ks = 0; ks < 8; ks++)
      wreg[tau][ks] = *(const bf16x8*)&wb[(tau * 8 + ks) * 512];
#pragma unroll
  for (int tt2 = 0; tt2 < 2; tt2++)
#pragma unroll
    for (int ks = 0; ks < 8; ks++) {
      bf16x8 v = *(const bf16x8*)&wb[((4 + tt2) * 8 + ks) * 512];
      *(bf16x8*)&wlds[((wv * 2 + tt2) * 8 + ks) * 512 + lane * 8] = v;
    }
  __syncthreads();

  int d4[4], seg4[4];
#pragma unroll
  for (int r = 0; r < 4; r++) {
    d4[r] = d_s[lgrp * 4 + r];
    seg4[r] = seg_s[lgrp * 4 + r];
  }
  int dmax = 0;
#pragma unroll
  for (int q = 0; q < 16; q++) dmax = max(dmax, d_s[q]);

  const int i0 = wv * 32 + lrow;
  const float* bh = dir ? bhhb : bhhf;
  float bias[3][2];
#pragma unroll
  for (int g = 0; g < 3; g++)
#pragma unroll
    for (int a = 0; a < 2; a++) bias[g][a] = bh[g * 256 + i0 + 16 * a];

  float h[4][2] = {};

  for (int t = 0; t < dmax; t++) {
    const int cur = t & 1;
    float gx[4][3][2];
#pragma unroll
    for (int r = 0; r < 4; r++) {
      if (t < d4[r]) {
        int ts = dir ? (d4[r] - 1 - t) : t;
        const float* grow = G + (size_t)(seg4[r] * TT + ts) * 1536 + dir * G3;
#pragma unroll
        for (int g = 0; g < 3; g++)
#pragma unroll
          for (int a = 0; a < 2; a++) gx[r][g][a] = grow[g * 256 + i0 + 16 * a];
      }
    }
    f32x4 acc[6];
#pragma unroll
    for (int tau = 0; tau < 6; tau++) acc[tau] = (f32x4){0.f, 0.f, 0.f, 0.f};
#pragma unroll
    for (int ks = 0; ks < 8; ks++) {
      bf16x8 av = *(const bf16x8*)&h_lds[cur][lrow * HSTR + ks * 32 + lgrp * 8];
#pragma unroll
      for (int tau = 0; tau < 4; tau++)
        acc[tau] = __builtin_amdgcn_mfma_f32_16x16x32_bf16(av, wreg[tau][ks],
                                                           acc[tau], 0, 0, 0);
#pragma unroll
      for (int tt2 = 0; tt2 < 2; tt2++) {
        bf16x8 wf = *(const bf16x8*)&wlds[((wv * 2 + tt2) * 8 + ks) * 512 + lane * 8];
        acc[4 + tt2] = __builtin_amdgcn_mfma_f32_16x16x32_bf16(av, wf,
                                                               acc[4 + tt2], 0, 0, 0);
      }
    }
#pragma unroll
    for (int r = 0; r < 4; r++) {
      if (t < d4[r]) {
#pragma unroll
        for (int a = 0; a < 2; a++) {
          float rr = fsig(gx[r][0][a] + acc[a][r] + bias[0][a]);
          float zz = fsig(gx[r][1][a] + acc[2 + a][r] + bias[1][a]);
          float nn = ftanh(gx[r][2][a] + rr * (acc[4 + a][r] + bias[2][a]));
          h[r][a] = (1.f - zz) * nn + zz * h[r][a];
          h_lds[cur ^ 1][(lgrp * 4 + r) * HSTR + i0 + 16 * a] = (short)f2bf(h[r][a]);
        }
      }
    }
    __syncthreads();
  }

#pragma unroll
  for (int r = 0; r < 4; r++)
#pragma unroll
    for (int a = 0; a < 2; a++)
      out[(size_t)seg4[r] * 512 + dir * 256 + i0 + 16 * a] = h[r][a];
}

extern "C" void kernel_launch(void* const* d_in, const int* in_sizes, int n_in,
                              void* d_out, int out_size, void* d_ws, size_t ws_size,
                              hipStream_t stream) {
  const float* mel = (const float*)d_in[0];
  const int Mmel = in_sizes[0] / (BB * CC);
  const int* duration = (const int*)d_in[2];
  const int* src_len = (const int*)d_in[3];
  const float* conv1_w = (const float*)d_in[5];
  const float* bn1_g = (const float*)d_in[6];
  const float* bn1_b = (const float*)d_in[7];
  const float* conv2_w = (const float*)d_in[8];
  const float* bn2_g = (const float*)d_in[9];
  const float* bn2_b = (const float*)d_in[10];
  const float* w_ih_f = (const float*)d_in[11];
  const float* w_hh_f = (const float*)d_in[12];
  const float* b_ih_f = (const float*)d_in[13];
  const float* b_hh_f = (const float*)d_in[14];
  const float* w_ih_b = (const float*)d_in[15];
  const float* w_hh_b = (const float*)d_in[16];
  const float* b_ih_b = (const float*)d_in[17];
  const float* b_hh_b = (const float*)d_in[18];

  char* w = (char*)d_ws;
  int* starts = (int*)w;            w += 512 * sizeof(int);
  int* dur = (int*)w;               w += 512 * sizeof(int);
  int* perm = (int*)w;              w += 512 * sizeof(int);
  w += 512 * sizeof(int);           // pad
  float* xg = (float*)w;            w += (size_t)NSEG * TT * CC * sizeof(float);     // 2.62 MB
  float* G = (float*)w;             w += (size_t)NSEG * TT * 1536 * sizeof(float);   // 50.3 MB
  ushort* wp = (ushort*)w;          w += (size_t)2 * 8 * 6 * 8 * 512 * sizeof(ushort); // 786 KB
  ushort* wpc = (ushort*)w;         w += (size_t)12288 * sizeof(ushort);             // 24.6 KB
  (void)ws_size; (void)n_in; (void)out_size;

  k_prep<<<1, 512, 0, stream>>>(duration, src_len, starts, dur, perm);
  k_wpack<<<1536, 256, 0, stream>>>(w_hh_f, w_hh_b, wp);
  k_wpackc<<<48, 256, 0, stream>>>(conv1_w, bn1_g, bn1_b, conv2_w, wpc);
  k_conv<<<NSEG, 512, 0, stream>>>(mel, starts, dur, wpc, bn2_g, bn2_b, xg, Mmel);
  k_xgate<<<dim3(128, 24), 256, 0, stream>>>(xg, w_ih_f, w_ih_b, b_ih_f, b_ih_b, G);
  k_gru<<<64, 512, 0, stream>>>(G, wp, b_hh_f, b_hh_b, dur, perm, (float*)d_out);
}